// Round 17
// baseline (1008.856 us; speedup 1.0000x reference)
//
#include <hip/hip_runtime.h>
#include <hip/hip_bf16.h>
#include <math.h>

#define BB 16
#define TT 256
#define DIN 384
#define DD 512
#define LL 6
#define HH 8
#define PP 64
#define SS 10
#define BT (BB*TT)   // 4096

enum { ACT_NONE=0, ACT_RELU=1, ACT_TANH=2, ACT_SILU=3, ACT_RELU_TAIL=4 };

typedef __attribute__((ext_vector_type(8))) short bf16x8;
typedef __attribute__((ext_vector_type(4))) float f32x4;
typedef __hip_bfloat16 bh16;

typedef const __attribute__((address_space(1))) void gvoid_t;
typedef __attribute__((address_space(3))) void lvoid_t;
__device__ __forceinline__ void gload16(const void* g, void* l) {
    __builtin_amdgcn_global_load_lds((gvoid_t*)g, (lvoid_t*)l, 16, 0, 0);
}

__device__ __forceinline__ float b2f(unsigned short u) {
    return __uint_as_float(((unsigned int)u) << 16);
}

// bijective chunked XCD swizzle (m204) within one z-plane.
__device__ __forceinline__ void xcd_swizzle_always(int& bx, int& by) {
    int gx = gridDim.x;
    int nwg = gx * gridDim.y;
    int lid = by * gx + bx;
    int q = nwg >> 3, r = nwg & 7;
    int xcd = lid & 7, idx = lid >> 3;
    int swz = (xcd < r) ? (xcd * (q + 1) + idx) : (r * (q + 1) + (xcd - r) * q + idx);
    bx = swz % gx;
    by = swz / gx;
}
__device__ __forceinline__ void xcd_swizzle(int& bx, int& by) {
    if (gridDim.z == 1) xcd_swizzle_always(bx, by);
}

// =====================================================================================
// Generic bf16 MFMA GEMM: C = act(A @ Bt^T + bias)  (Bt stored [N][K])
__global__ __launch_bounds__(256) void mgemm_kernel(
    const bh16* __restrict__ A, int lda,
    const bh16* __restrict__ Bt, int ldb,
    const float* __restrict__ bias,
    float* __restrict__ Cf, bh16* __restrict__ Cb, int ldc,
    int N, int K, int shift, int accum, int act,
    const bh16* __restrict__ zp)
{
    __shared__ bf16x8 As[128*8];
    __shared__ bf16x8 Bs[64*8];

    int bx = blockIdx.x, by = blockIdx.y;
    xcd_swizzle(bx, by);

    const int tid  = threadIdx.x;
    const int lane = tid & 63, w = tid >> 6;
    const int wm = w >> 1, wn = w & 1;
    const int row0 = by * 128, col0 = bx * 64;

    f32x4 acc[4][2];
    #pragma unroll
    for (int i = 0; i < 4; ++i)
        #pragma unroll
        for (int j = 0; j < 2; ++j) acc[i][j] = (f32x4){0.f,0.f,0.f,0.f};

    const int nkt = K >> 6;
    for (int kt = 0; kt < nkt; ++kt) {
        int k0 = kt << 6;
        #pragma unroll
        for (int j = 0; j < 4; ++j) {
            int c = ((w*4 + j) << 6) + lane;
            int row = c >> 3, chk = c & 7;
            int schk = chk ^ (row & 7);
            int grow = row0 + row;
            const bh16* src = ((grow & 255) >= shift)
                ? (A + (size_t)(grow - shift)*lda + k0 + schk*8) : zp;
            gload16(src, &As[(w*4 + j) * 64]);
        }
        #pragma unroll
        for (int j = 0; j < 2; ++j) {
            int c = ((w*2 + j) << 6) + lane;
            int row = c >> 3, chk = c & 7;
            int schk = chk ^ (row & 7);
            int gcol = col0 + row;
            const bh16* src = (gcol < N)
                ? (Bt + (size_t)gcol*ldb + k0 + schk*8) : zp;
            gload16(src, &Bs[(w*2 + j) * 64]);
        }
        asm volatile("s_waitcnt vmcnt(0)" ::: "memory");
        __syncthreads();

        bf16x8 a[4][2], b[2][2];
        #pragma unroll
        for (int fm = 0; fm < 4; ++fm) {
            int row = wm*64 + fm*16 + (lane & 15);
            #pragma unroll
            for (int ks = 0; ks < 2; ++ks)
                a[fm][ks] = As[row*8 + ((ks*4 + (lane>>4)) ^ (row & 7))];
        }
        #pragma unroll
        for (int fn = 0; fn < 2; ++fn) {
            int col = wn*32 + fn*16 + (lane & 15);
            #pragma unroll
            for (int ks = 0; ks < 2; ++ks)
                b[fn][ks] = Bs[col*8 + ((ks*4 + (lane>>4)) ^ (col & 7))];
        }
        #pragma unroll
        for (int ks = 0; ks < 2; ++ks)
            #pragma unroll
            for (int fm = 0; fm < 4; ++fm)
                #pragma unroll
                for (int fn = 0; fn < 2; ++fn)
                    acc[fm][fn] = __builtin_amdgcn_mfma_f32_16x16x32_bf16(
                        a[fm][ks], b[fn][ks], acc[fm][fn], 0, 0, 0);
        __syncthreads();
    }

    #pragma unroll
    for (int fm = 0; fm < 4; ++fm) {
        #pragma unroll
        for (int fn = 0; fn < 2; ++fn) {
            int gc = col0 + wn*32 + fn*16 + (lane & 15);
            float bs = bias ? bias[gc] : 0.f;
            #pragma unroll
            for (int r = 0; r < 4; ++r) {
                int gr = row0 + wm*64 + fm*16 + (lane>>4)*4 + r;
                float v = acc[fm][fn][r] + bs;
                if (act == ACT_RELU) v = fmaxf(v, 0.f);
                else if (act == ACT_RELU_TAIL && gc >= 1536) v = fmaxf(v, 0.f);
                size_t o = (size_t)gr*ldc + gc;
                if (Cf) { if (accum) Cf[o] += v; else Cf[o] = v; }
                if (Cb) Cb[o] = __float2bfloat16(v);
            }
        }
    }
}

// =====================================================================================
// Fused attention: norms + QK^T + hyperbolic softmax + V-transpose + PV, one kernel.
__global__ __launch_bounds__(256) void fattn_kernel(
    const bh16* __restrict__ qkv,      // [4096][1600]: q@0, k@+512, v@+1024
    const float* __restrict__ curv,
    bh16* __restrict__ gmb)            // [4096][512]
{
    __shared__ bf16x8 Qs[64*8];
    __shared__ bf16x8 Ks[256*8];
    __shared__ __align__(16) bh16 Ps[64*64];
    __shared__ bf16x8 Bv[64*8];
    __shared__ unsigned short Vst[64*72];
    __shared__ float redA[2][64];
    __shared__ float redB[2][64];
    __shared__ float qnS[64];
    __shared__ float knS[256];

    const int rh = blockIdx.x;
    const int bh = blockIdx.y;
    const int b = bh >> 3, hh = bh & 7;
    const int lane = threadIdx.x & 63, w = threadIdx.x >> 6;
    const int wm = w >> 1, wn = w & 1;

    const bh16* qbase = qkv + hh * 64;
    const bh16* kbase = qkv + 512 + hh * 64;
    #pragma unroll
    for (int j = 0; j < 2; ++j) {
        int c = ((w*2 + j) << 6) + lane;
        int row = c >> 3, chk = c & 7, schk = chk ^ (row & 7);
        gload16(qbase + (size_t)(b*256 + rh*64 + row)*1600 + schk*8, &Qs[(w*2+j)*64]);
    }
    #pragma unroll
    for (int j = 0; j < 8; ++j) {
        int c = ((w*8 + j) << 6) + lane;
        int row = c >> 3, chk = c & 7, schk = chk ^ (row & 7);
        gload16(kbase + (size_t)(b*256 + row)*1600 + schk*8, &Ks[(w*8+j)*64]);
    }
    asm volatile("s_waitcnt vmcnt(0)" ::: "memory");
    __syncthreads();

    {
        int t = threadIdx.x;
        float s = 0.f;
        #pragma unroll
        for (int jj = 0; jj < 8; ++jj) {
            bf16x8 v = Ks[t*8 + ((t + jj) & 7)];
            #pragma unroll
            for (int e = 0; e < 8; ++e) { float f = b2f((unsigned short)v[e]); s += f * f; }
        }
        knS[t] = s;
        if (t < 64) {
            float sq = 0.f;
            #pragma unroll
            for (int jj = 0; jj < 8; ++jj) {
                bf16x8 v = Qs[t*8 + ((t + jj) & 7)];
                #pragma unroll
                for (int e = 0; e < 8; ++e) { float f = b2f((unsigned short)v[e]); sq += f * f; }
            }
            qnS[t] = sq;
        }
    }
    __syncthreads();

    f32x4 acc[2][8];
    #pragma unroll
    for (int i = 0; i < 2; ++i)
        #pragma unroll
        for (int j = 0; j < 8; ++j) acc[i][j] = (f32x4){0.f,0.f,0.f,0.f};

    bf16x8 af[2][2];
    #pragma unroll
    for (int fm = 0; fm < 2; ++fm) {
        int row = wm*32 + fm*16 + (lane & 15);
        #pragma unroll
        for (int ks = 0; ks < 2; ++ks)
            af[fm][ks] = Qs[row*8 + ((ks*4 + (lane>>4)) ^ (row & 7))];
    }
    #pragma unroll
    for (int fn = 0; fn < 8; ++fn) {
        int col = wn*128 + fn*16 + (lane & 15);
        #pragma unroll
        for (int ks = 0; ks < 2; ++ks) {
            bf16x8 bf = Ks[col*8 + ((ks*4 + (lane>>4)) ^ (col & 7))];
            #pragma unroll
            for (int fm = 0; fm < 2; ++fm)
                acc[fm][fn] = __builtin_amdgcn_mfma_f32_16x16x32_bf16(
                    af[fm][ks], bf, acc[fm][fn], 0, 0, 0);
        }
    }

    const float c_ = fabsf(curv[hh]) + 1e-8f;
    const float isc = 1.f / sqrtf(c_);
    float qnv[2][4], knv[8];
    #pragma unroll
    for (int fm = 0; fm < 2; ++fm)
        #pragma unroll
        for (int r = 0; r < 4; ++r)
            qnv[fm][r] = qnS[wm*32 + fm*16 + (lane>>4)*4 + r];
    #pragma unroll
    for (int fn = 0; fn < 8; ++fn)
        knv[fn] = knS[wn*128 + fn*16 + (lane & 15)];

    float rmax[2][4];
    #pragma unroll
    for (int fm = 0; fm < 2; ++fm)
        #pragma unroll
        for (int r = 0; r < 4; ++r) rmax[fm][r] = -1e30f;
    #pragma unroll
    for (int fm = 0; fm < 2; ++fm)
        #pragma unroll
        for (int fn = 0; fn < 8; ++fn)
            #pragma unroll
            for (int r = 0; r < 4; ++r) {
                float s = acc[fm][fn][r];
                float d2 = fmaxf(qnv[fm][r] + knv[fn] - 2.f * s, 0.f);
                float denom = fmaxf((1.f - c_ * qnv[fm][r]) * (1.f - c_ * knv[fn]), 1e-5f);
                float arg = fmaxf(1.f + (2.f * c_ * d2) / denom, 1.00001f);
                float dist = logf(arg + sqrtf((arg - 1.f) * (arg + 1.f))) * isc;
                float lg = -dist;
                acc[fm][fn][r] = lg;
                rmax[fm][r] = fmaxf(rmax[fm][r], lg);
            }
    #pragma unroll
    for (int off = 1; off < 16; off <<= 1)
        #pragma unroll
        for (int fm = 0; fm < 2; ++fm)
            #pragma unroll
            for (int r = 0; r < 4; ++r)
                rmax[fm][r] = fmaxf(rmax[fm][r], __shfl_xor(rmax[fm][r], off));
    if ((lane & 15) == 0)
        #pragma unroll
        for (int fm = 0; fm < 2; ++fm)
            #pragma unroll
            for (int r = 0; r < 4; ++r)
                redA[wn][wm*32 + fm*16 + (lane>>4)*4 + r] = rmax[fm][r];
    __syncthreads();
    #pragma unroll
    for (int fm = 0; fm < 2; ++fm)
        #pragma unroll
        for (int r = 0; r < 4; ++r)
            rmax[fm][r] = fmaxf(rmax[fm][r], redA[wn ^ 1][wm*32 + fm*16 + (lane>>4)*4 + r]);
    float rsum[2][4];
    #pragma unroll
    for (int fm = 0; fm < 2; ++fm)
        #pragma unroll
        for (int r = 0; r < 4; ++r) rsum[fm][r] = 0.f;
    #pragma unroll
    for (int fm = 0; fm < 2; ++fm)
        #pragma unroll
        for (int fn = 0; fn < 8; ++fn)
            #pragma unroll
            for (int r = 0; r < 4; ++r) {
                float e = expf(acc[fm][fn][r] - rmax[fm][r]);
                acc[fm][fn][r] = e;
                rsum[fm][r] += e;
            }
    #pragma unroll
    for (int off = 1; off < 16; off <<= 1)
        #pragma unroll
        for (int fm = 0; fm < 2; ++fm)
            #pragma unroll
            for (int r = 0; r < 4; ++r)
                rsum[fm][r] += __shfl_xor(rsum[fm][r], off);
    if ((lane & 15) == 0)
        #pragma unroll
        for (int fm = 0; fm < 2; ++fm)
            #pragma unroll
            for (int r = 0; r < 4; ++r)
                redB[wn][wm*32 + fm*16 + (lane>>4)*4 + r] = rsum[fm][r];
    __syncthreads();
    float pinv[2][4];
    #pragma unroll
    for (int fm = 0; fm < 2; ++fm)
        #pragma unroll
        for (int r = 0; r < 4; ++r)
            pinv[fm][r] = 1.f / (rsum[fm][r] + redB[wn ^ 1][wm*32 + fm*16 + (lane>>4)*4 + r]);

    f32x4 acc2[2][2];
    #pragma unroll
    for (int i = 0; i < 2; ++i)
        #pragma unroll
        for (int j = 0; j < 2; ++j) acc2[i][j] = (f32x4){0.f,0.f,0.f,0.f};

    const bh16* vbase = qkv + 1024 + hh * 64;
    for (int kt = 0; kt < 4; ++kt) {
        __syncthreads();
        if (wn == (kt >> 1)) {
            int fnb = (kt & 1) * 4;
            #pragma unroll
            for (int fm = 0; fm < 2; ++fm)
                #pragma unroll
                for (int fnl = 0; fnl < 4; ++fnl)
                    #pragma unroll
                    for (int r = 0; r < 4; ++r) {
                        int rowl = wm*32 + fm*16 + (lane>>4)*4 + r;
                        int kl = fnl*16 + (lane & 15);
                        float p = acc[fm][fnb + fnl][r] * pinv[fm][r];
                        Ps[(rowl*8 + ((kl >> 3) ^ (rowl & 7)))*8 + (kl & 7)] = __float2bfloat16(p);
                    }
        }
        #pragma unroll
        for (int j = 0; j < 2; ++j) {
            int c = threadIdx.x + j*256;
            int tr = c >> 3, chk = c & 7;
            bf16x8 v = *(const bf16x8*)(vbase + (size_t)(b*256 + kt*64 + tr)*1600 + chk*8);
            *(bf16x8*)(&Vst[tr*72 + chk*8]) = v;
        }
        __syncthreads();
        #pragma unroll
        for (int j = 0; j < 2; ++j) {
            int c = threadIdx.x + j*256;
            int col = c & 63, chk = c >> 6;
            bf16x8 v;
            #pragma unroll
            for (int e = 0; e < 8; ++e)
                v[e] = (short)Vst[(chk*8 + e)*72 + col];
            Bv[col*8 + (chk ^ (col & 7))] = v;
        }
        __syncthreads();

        bf16x8 pa[2][2], vb[2][2];
        #pragma unroll
        for (int fm = 0; fm < 2; ++fm) {
            int row = wm*32 + fm*16 + (lane & 15);
            #pragma unroll
            for (int ks = 0; ks < 2; ++ks)
                pa[fm][ks] = ((bf16x8*)Ps)[row*8 + ((ks*4 + (lane>>4)) ^ (row & 7))];
        }
        #pragma unroll
        for (int fn = 0; fn < 2; ++fn) {
            int col = wn*32 + fn*16 + (lane & 15);
            #pragma unroll
            for (int ks = 0; ks < 2; ++ks)
                vb[fn][ks] = Bv[col*8 + ((ks*4 + (lane>>4)) ^ (col & 7))];
        }
        #pragma unroll
        for (int ks = 0; ks < 2; ++ks)
            #pragma unroll
            for (int fm = 0; fm < 2; ++fm)
                #pragma unroll
                for (int fn = 0; fn < 2; ++fn)
                    acc2[fm][fn] = __builtin_amdgcn_mfma_f32_16x16x32_bf16(
                        pa[fm][ks], vb[fn][ks], acc2[fm][fn], 0, 0, 0);
    }

    #pragma unroll
    for (int fm = 0; fm < 2; ++fm)
        #pragma unroll
        for (int fn = 0; fn < 2; ++fn)
            #pragma unroll
            for (int r = 0; r < 4; ++r) {
                int rowl = wm*32 + fm*16 + (lane>>4)*4 + r;
                int col = wn*32 + fn*16 + (lane & 15);
                gmb[((size_t)(b*256 + rh*64 + rowl))*512 + hh*64 + col] =
                    __float2bfloat16(acc2[fm][fn][r]);
            }
}

// =====================================================================================
// Merged wave4 + topo: blocks 0..1023 = wavelet, 1024..1279 = topo. LDS union ~25KB.
union WTSmem {
    struct { float dtile[66*64]; float ftile[32*64]; } wv;
    struct { bf16x8 As[128*8]; bf16x8 Bs[64*8]; float redT[2][128]; float bsumS; } tp;
};

__global__ __launch_bounds__(256) void midwt_kernel(
    // wavelet
    const bh16* __restrict__ hb,
    const float* __restrict__ wav0, const float* __restrict__ wav1,
    const float* __restrict__ wav2, const float* __restrict__ wav3,
    int l, bh16* __restrict__ comb,
    // topo
    const bh16* __restrict__ t1,
    const bh16* __restrict__ te2T, const float* __restrict__ te2b,
    const bh16* __restrict__ td1T, const float* __restrict__ td1b,
    const float* __restrict__ bdw, const float* __restrict__ bdb,
    float* __restrict__ loss, bh16* __restrict__ tdb)
{
    __shared__ WTSmem sm;
    const int bid = blockIdx.x;
    const int tid = threadIdx.x;

    if (bid < 1024) {
        // ------------- wavelet branch -------------
        float* dtile = sm.wv.dtile;
        float* ftile = sm.wv.ftile;
        const int dblk = bid & 7;
        const int iy = (bid >> 3) & 7;
        const int b = bid >> 6;
        const int i = iy >> 1, thalf = iy & 1;
        const int Karr[4] = {4, 8, 16, 32};
        const int K = Karr[i], sv = 2 << i, Ti = 128 >> i;
        const int dbase = dblk * 64;
        if (tid < 64) {
            const float* wsrc = (i == 0) ? wav0 : (i == 1) ? wav1 : (i == 2) ? wav2 : wav3;
            const float* row = wsrc + ((size_t)l * DD + dbase + tid) * K;
            float mx = -1e30f;
            for (int k = 0; k < K; ++k) mx = fmaxf(mx, row[k]);
            float s = 0.f;
            for (int k = 0; k < K; ++k) { float e = expf(row[k] - mx); ftile[k*64 + tid] = e; s += e; }
            float inv = 1.f / s;
            for (int k = 0; k < K; ++k) ftile[k*64 + tid] *= inv;
        }
        const float invsv = 1.f / (float)sv;
        const int t0 = thalf * 128;
        float p0 = ((float)t0 + 0.5f) * invsv - 0.5f;
        p0 = fminf(fmaxf(p0, 0.f), (float)(Ti - 1));
        const int jbase = (int)p0;
        float p1 = ((float)(t0 + 127) + 0.5f) * invsv - 0.5f;
        p1 = fminf(fmaxf(p1, 0.f), (float)(Ti - 1));
        const int him = min((int)p1 + 1, Ti - 1);
        const int jcount = him - jbase + 1;     // <= 66
        __syncthreads();
        const bh16* hcol = hb + (size_t)b * (TT * DD) + dbase;
        for (int e = tid; e < jcount * 64; e += 256) {
            int jl = e >> 6, d0 = e & 63;
            int j = jbase + jl;
            int tb = j * sv - (K - 1);
            float acc = 0.f;
            #pragma unroll 4
            for (int k = 0; k < K; ++k) {
                int t = tb + k;
                if (t >= 0)
                    acc += b2f(*(const unsigned short*)(hcol + (size_t)t * DD + d0)) * ftile[k * 64 + d0];
            }
            dtile[jl * 64 + d0] = acc;
        }
        __syncthreads();
        for (int e = tid; e < 128 * 64; e += 256) {
            int tl = e >> 6, d0 = e & 63;
            int t = t0 + tl;
            float pos = ((float)t + 0.5f) * invsv - 0.5f;
            pos = fminf(fmaxf(pos, 0.f), (float)(Ti - 1));
            int lo = (int)pos;
            int hi = min(lo + 1, Ti - 1);
            float w = pos - (float)lo;
            float v = dtile[(lo - jbase) * 64 + d0] * (1.f - w) + dtile[(hi - jbase) * 64 + d0] * w;
            comb[((size_t)b * TT + t) * 2048 + i * 512 + dbase + d0] = __float2bfloat16(v);
        }
        return;
    }

    // ------------- topo branch -------------
    bf16x8* As = sm.tp.As;
    bf16x8* Bs = sm.tp.Bs;
    const int lid = bid - 1024;
    const int bx = lid & 7, by = lid >> 3;
    const int lane = tid & 63, w = tid >> 6;
    const int wm = w >> 1, wn = w & 1;
    const int row0 = by * 128;

    #pragma unroll
    for (int j = 0; j < 4; ++j) {
        int c = ((w*4 + j) << 6) + lane;
        int row = c >> 3, chk = c & 7, schk = chk ^ (row & 7);
        gload16(t1 + (size_t)(row0 + row)*1600 + schk*8, &As[(w*4+j)*64]);
    }
    #pragma unroll
    for (int j = 0; j < 2; ++j) {
        int c = ((w*2 + j) << 6) + lane;
        int row = c >> 3, chk = c & 7, schk = chk ^ (row & 7);
        gload16(te2T + (size_t)row*64 + schk*8, &Bs[(w*2+j)*64]);
    }
    asm volatile("s_waitcnt vmcnt(0)" ::: "memory");
    __syncthreads();

    f32x4 acc[4][2];
    #pragma unroll
    for (int i = 0; i < 4; ++i)
        #pragma unroll
        for (int j = 0; j < 2; ++j) acc[i][j] = (f32x4){0.f,0.f,0.f,0.f};
    {
        bf16x8 a[4][2], b[2][2];
        #pragma unroll
        for (int fm = 0; fm < 4; ++fm) {
            int row = wm*64 + fm*16 + (lane & 15);
            #pragma unroll
            for (int ks = 0; ks < 2; ++ks)
                a[fm][ks] = As[row*8 + ((ks*4 + (lane>>4)) ^ (row & 7))];
        }
        #pragma unroll
        for (int fn = 0; fn < 2; ++fn) {
            int col = wn*32 + fn*16 + (lane & 15);
            #pragma unroll
            for (int ks = 0; ks < 2; ++ks)
                b[fn][ks] = Bs[col*8 + ((ks*4 + (lane>>4)) ^ (col & 7))];
        }
        #pragma unroll
        for (int ks = 0; ks < 2; ++ks)
            #pragma unroll
            for (int fm = 0; fm < 4; ++fm)
                #pragma unroll
                for (int fn = 0; fn < 2; ++fn)
                    acc[fm][fn] = __builtin_amdgcn_mfma_f32_16x16x32_bf16(
                        a[fm][ks], b[fn][ks], acc[fm][fn], 0, 0, 0);
    }
    #pragma unroll
    for (int fn = 0; fn < 2; ++fn) {
        int gc = wn*32 + fn*16 + (lane & 15);
        float bs = te2b[gc];
        #pragma unroll
        for (int fm = 0; fm < 4; ++fm)
            #pragma unroll
            for (int r = 0; r < 4; ++r) acc[fm][fn][r] += bs;
    }

    if (bx == 0) {
        float bconst = (bdb[0] - bdb[1]) + 0.1f;
        float wv[2];
        #pragma unroll
        for (int fn = 0; fn < 2; ++fn) {
            int gc = wn*32 + fn*16 + (lane & 15);
            wv[fn] = bdw[gc*2] - bdw[gc*2 + 1];
        }
        float dp[4][4];
        #pragma unroll
        for (int fm = 0; fm < 4; ++fm)
            #pragma unroll
            for (int r = 0; r < 4; ++r) {
                dp[fm][r] = acc[fm][0][r]*wv[0] + acc[fm][1][r]*wv[1];
                #pragma unroll
                for (int off = 1; off < 16; off <<= 1)
                    dp[fm][r] += __shfl_xor(dp[fm][r], off);
            }
        if ((lane & 15) == 0)
            #pragma unroll
            for (int fm = 0; fm < 4; ++fm)
                #pragma unroll
                for (int r = 0; r < 4; ++r)
                    sm.tp.redT[wn][wm*64 + fm*16 + (lane>>4)*4 + r] = dp[fm][r];
        if (tid == 0) sm.tp.bsumS = 0.f;
        __syncthreads();
        if (wn == 0 && (lane & 15) == 0) {
            float ls = 0.f;
            #pragma unroll
            for (int fm = 0; fm < 4; ++fm)
                #pragma unroll
                for (int r = 0; r < 4; ++r) {
                    int rowl = wm*64 + fm*16 + (lane>>4)*4 + r;
                    ls += fmaxf(dp[fm][r] + sm.tp.redT[1][rowl] + bconst, 0.f);
                }
            atomicAdd(&sm.tp.bsumS, ls);
        }
        __syncthreads();
        if (tid == 0) atomicAdd(loss, sm.tp.bsumS * (1.f / 4096.f));
    }

    __syncthreads();
    #pragma unroll
    for (int fm = 0; fm < 4; ++fm)
        #pragma unroll
        for (int fn = 0; fn < 2; ++fn)
            #pragma unroll
            for (int r = 0; r < 4; ++r) {
                int rowl = wm*64 + fm*16 + (lane>>4)*4 + r;
                int gc = wn*32 + fn*16 + (lane & 15);
                ((bh16*)As)[(rowl*8 + ((gc >> 3) ^ (rowl & 7)))*8 + (gc & 7)] =
                    __float2bfloat16(acc[fm][fn][r]);
            }
    #pragma unroll
    for (int j = 0; j < 2; ++j) {
        int c = ((w*2 + j) << 6) + lane;
        int row = c >> 3, chk = c & 7, schk = chk ^ (row & 7);
        gload16(td1T + (size_t)(bx*64 + row)*64 + schk*8, &Bs[(w*2+j)*64]);
    }
    asm volatile("s_waitcnt vmcnt(0)" ::: "memory");
    __syncthreads();

    f32x4 acc2[4][2];
    #pragma unroll
    for (int i = 0; i < 4; ++i)
        #pragma unroll
        for (int j = 0; j < 2; ++j) acc2[i][j] = (f32x4){0.f,0.f,0.f,0.f};
    {
        bf16x8 a[4][2], b[2][2];
        #pragma unroll
        for (int fm = 0; fm < 4; ++fm) {
            int row = wm*64 + fm*16 + (lane & 15);
            #pragma unroll
            for (int ks = 0; ks < 2; ++ks)
                a[fm][ks] = As[row*8 + ((ks*4 + (lane>>4)) ^ (row & 7))];
        }
        #pragma unroll
        for (int fn = 0; fn < 2; ++fn) {
            int col = wn*32 + fn*16 + (lane & 15);
            #pragma unroll
            for (int ks = 0; ks < 2; ++ks)
                b[fn][ks] = Bs[col*8 + ((ks*4 + (lane>>4)) ^ (col & 7))];
        }
        #pragma unroll
        for (int ks = 0; ks < 2; ++ks)
            #pragma unroll
            for (int fm = 0; fm < 4; ++fm)
                #pragma unroll
                for (int fn = 0; fn < 2; ++fn)
                    acc2[fm][fn] = __builtin_amdgcn_mfma_f32_16x16x32_bf16(
                        a[fm][ks], b[fn][ks], acc2[fm][fn], 0, 0, 0);
    }
    #pragma unroll
    for (int fm = 0; fm < 4; ++fm)
        #pragma unroll
        for (int fn = 0; fn < 2; ++fn) {
            int gcol = bx*64 + wn*32 + fn*16 + (lane & 15);
            float bs = td1b[gcol];
            #pragma unroll
            for (int r = 0; r < 4; ++r) {
                int gr = row0 + wm*64 + fm*16 + (lane>>4)*4 + r;
                tdb[(size_t)gr*512 + gcol] = __float2bfloat16(fmaxf(acc2[fm][fn][r] + bs, 0.f));
            }
        }
}

// =====================================================================================
// Fused 4-segment GEMM, split-K=4 over blockIdx.z (18 kt each)
__global__ __launch_bounds__(256) void fgemm_kernel(
    const bh16* __restrict__ A0, const bh16* __restrict__ A1,
    const bh16* __restrict__ A2, const bh16* __restrict__ A3,
    const bh16* __restrict__ B0, const bh16* __restrict__ B1,
    const bh16* __restrict__ B2, const bh16* __restrict__ B3,
    const float* __restrict__ bias,
    float* __restrict__ Cf0, float* __restrict__ Cf1,
    float* __restrict__ Cf2, float* __restrict__ Cf3,
    int dil, const bh16* __restrict__ zp)
{
    __shared__ bf16x8 As[128*8];
    __shared__ bf16x8 Bs[64*8];

    int bx = blockIdx.x, by = blockIdx.y;
    xcd_swizzle_always(bx, by);
    const int zz = blockIdx.z;
    const int ktlo = zz * 18;
    const int kthi = ktlo + 18;

    const int tid  = threadIdx.x;
    const int lane = tid & 63, w = tid >> 6;
    const int wm = w >> 1, wn = w & 1;
    const int row0 = by * 128, col0 = bx * 64;

    f32x4 acc[4][2];
    #pragma unroll
    for (int i = 0; i < 4; ++i)
        #pragma unroll
        for (int j = 0; j < 2; ++j) acc[i][j] = (f32x4){0.f,0.f,0.f,0.f};

    for (int kt = ktlo; kt < kthi; ++kt) {
        const bh16* Aseg; const bh16* Bseg;
        int ldas, ldbs, k0, mask_sh, addr_sh;
        if (kt < 8) {
            Aseg = A0; Bseg = B0; ldas = 512; ldbs = 512;
            k0 = kt << 6; mask_sh = 0; addr_sh = 0;
        } else if (kt < 40) {
            Aseg = A1; Bseg = B1; ldas = 2048; ldbs = 2048;
            k0 = (kt - 8) << 6; mask_sh = 0; addr_sh = 0;
        } else if (kt < 48) {
            Aseg = A2; Bseg = B2; ldas = 512; ldbs = 512;
            k0 = (kt - 40) << 6; mask_sh = 0; addr_sh = 0;
        } else {
            int kl = kt - 48, tap = kl >> 3;
            Aseg = A3; Bseg = B3; ldas = 512; ldbs = 1536;
            k0 = kl << 6;
            mask_sh = (2 - tap) * dil;
            addr_sh = mask_sh + tap;
        }
        #pragma unroll
        for (int j = 0; j < 4; ++j) {
            int c = ((w*4 + j) << 6) + lane;
            int row = c >> 3, chk = c & 7;
            int schk = chk ^ (row & 7);
            int grow = row0 + row;
            const bh16* src = ((grow & 255) >= mask_sh)
                ? (Aseg + (size_t)(grow - addr_sh)*ldas + k0 + schk*8) : zp;
            gload16(src, &As[(w*4 + j) * 64]);
        }
        #pragma unroll
        for (int j = 0; j < 2; ++j) {
            int c = ((w*2 + j) << 6) + lane;
            int row = c >> 3, chk = c & 7;
            int schk = chk ^ (row & 7);
            int gcol = col0 + row;
            gload16(Bseg + (size_t)gcol*ldbs + k0 + schk*8, &Bs[(w*2 + j) * 64]);
        }
        asm volatile("s_waitcnt vmcnt(0)" ::: "memory");
        __syncthreads();

        bf16x8 a[4][2], b[2][2];
        #pragma unroll
        for (int fm = 0; fm < 4; ++fm) {
            int row = wm*64 + fm*16 + (lane & 15);
            #pragma unroll
            for (int ks = 0; ks < 2; ++ks)
                a[fm][ks] = As[row*8 + ((ks*4 + (lane>>4)) ^ (row & 7))];
        }
        #pragma unroll
        for (int fn = 0; fn < 2; ++fn) {
            int col = wn*32 + fn*16 + (lane & 15);
            #pragma unroll
            for (int ks = 0; ks < 2; ++ks)
                b[fn][ks] = Bs[col*8 + ((ks*4 + (lane>>4)) ^ (col & 7))];
        }
        #pragma unroll
        for (int ks = 0; ks < 2; ++ks)
            #pragma unroll
            for (int fm = 0; fm < 4; ++fm)
                #pragma unroll
                for (int fn = 0; fn < 2; ++fn)
                    acc[fm][fn] = __builtin_amdgcn_mfma_f32_16x16x32_bf16(
                        a[fm][ks], b[fn][ks], acc[fm][fn], 0, 0, 0);
        __syncthreads();
    }

    float* Cf = (zz == 0) ? Cf0 : (zz == 1) ? Cf1 : (zz == 2) ? Cf2 : Cf3;
    #pragma unroll
    for (int fm = 0; fm < 4; ++fm) {
        #pragma unroll
        for (int fn = 0; fn < 2; ++fn) {
            int gc = col0 + wn*32 + fn*16 + (lane & 15);
            float bs = (zz == 0) ? bias[gc] : 0.f;
            #pragma unroll
            for (int r = 0; r < 4; ++r) {
                int gr = row0 + wm*64 + fm*16 + (lane>>4)*4 + r;
                Cf[(size_t)gr*512 + gc] = acc[fm][fn][r] + bs;
            }
        }
    }
}

// =====================================================================================
// Small-M (M=16) MFMA GEMM, one wave = 16x16xK tile, no LDS.
__global__ __launch_bounds__(256) void hgemm16_kernel(
    const bh16* __restrict__ A, int lda, long aZ,
    const bh16* __restrict__ Bt, int ldb,
    const float* __restrict__ bias,
    const float* __restrict__ pre,
    float* __restrict__ Of, bh16* __restrict__ Ob, long oZ,
    int N, int K, int act,
    float* __restrict__ curf, bh16* __restrict__ curb,
    const float* __restrict__ scaleptr)
{
    const int z = blockIdx.z;
    A += (long)z * aZ;
    const int lane = threadIdx.x & 63, w = threadIdx.x >> 6;
    const int col0 = blockIdx.x * 64 + w * 16;
    const int ar = lane & 15;
    const int koff = (lane >> 4) * 8;
    const bh16* arow = A + (size_t)ar * lda + koff;
    const bh16* brow = Bt + (size_t)(col0 + ar) * ldb + koff;
    f32x4 acc = {0.f, 0.f, 0.f, 0.f};
    const int nkt = K >> 5;
    for (int kt0 = 0; kt0 < nkt; kt0 += 8) {
        bf16x8 av[8], bv[8];
        #pragma unroll
        for (int j = 0; j < 8; ++j) {
            av[j] = *(const bf16x8*)(arow + (size_t)(kt0 + j) * 32);
            bv[j] = *(const bf16x8*)(brow + (size_t)(kt0 + j) * 32);
        }
        #pragma unroll
        for (int j = 0; j < 8; ++j)
            acc = __builtin_amdgcn_mfma_f32_16x16x32_bf16(av[j], bv[j], acc, 0, 0, 0);
    }
    const int col = col0 + ar;
    float bs = bias ? bias[col] : 0.f;
    float sc = scaleptr ? *scaleptr : 0.f;
    #pragma unroll
    for (int r = 0; r < 4; ++r) {
        int row = (lane >> 4) * 4 + r;
        float v = acc[r] + bs;
        if (pre) v += pre[(size_t)row * N + col];
        if (act == ACT_SILU)      v = v / (1.f + expf(-v));
        else if (act == ACT_TANH) v = tanhf(v);
        if (curf) {
            size_t o = (size_t)row * 512 + col;
            float nc = curf[o] - v * sc;
            curf[o] = nc;
            curb[o] = __float2bfloat16(nc);
        } else {
            size_t o = (size_t)z * oZ + (size_t)row * N + col;
            if (Of) Of[o] = v;
            if (Ob) Ob[o] = __float2bfloat16(v);
        }
    }
}

// ---------------- head3 helpers ----------------
// preload 64x512 weight slice into 16 bf16x8 regs
__device__ __forceinline__ void bload512(const bh16* Bt, int ldb, int col0, int lane, bf16x8 bv[16])
{
    const int ar = lane & 15;
    const int koff = (lane >> 4) * 8;
    const bh16* brow = Bt + (size_t)(col0 + ar) * ldb + koff;
    #pragma unroll
    for (int j = 0; j < 16; ++j)
        bv[j] = *(const bf16x8*)(brow + (size_t)j * 32);
}

// GEMV K=512: A from LDS (padded lda), B from preloaded regs. Same accumulation order
// as hgemm16 (sequential j) -> bit-identical.
__device__ __forceinline__ f32x4 lmfma512(const unsigned short* A, int lda, int lane, const bf16x8 bv[16])
{
    const int ar = lane & 15;
    const int koff = (lane >> 4) * 8;
    const unsigned short* arow = A + (size_t)ar * lda + koff;
    f32x4 acc = {0.f, 0.f, 0.f, 0.f};
    #pragma unroll
    for (int j = 0; j < 16; ++j) {
        bf16x8 av = *(const bf16x8*)(arow + (size_t)j * 32);
        acc = __builtin_amdgcn_mfma_f32_16x16x32_bf16(av, bv[j], acc, 0, 0, 0);
    }
    return acc;
}

// direct-B GEMV for mm1 (K=1024)
__device__ __forceinline__ f32x4 lslice(const unsigned short* A, int lda, const bh16* Bt, int ldb,
                                        int col0, int K, int lane)
{
    const int ar = lane & 15;
    const int koff = (lane >> 4) * 8;
    const unsigned short* arow = A + (size_t)ar * lda + koff;
    const bh16* brow = Bt + (size_t)(col0 + ar) * ldb + koff;
    f32x4 acc = {0.f, 0.f, 0.f, 0.f};
    const int nkt = K >> 5;
    for (int kt0 = 0; kt0 < nkt; kt0 += 8) {
        bf16x8 av[8], bv[8];
        #pragma unroll
        for (int j = 0; j < 8; ++j) {
            av[j] = *(const bf16x8*)(arow + (size_t)(kt0 + j) * 32);
            bv[j] = *(const bf16x8*)(brow + (size_t)(kt0 + j) * 32);
        }
        #pragma unroll
        for (int j = 0; j < 8; ++j)
            acc = __builtin_amdgcn_mfma_f32_16x16x32_bf16(av[j], bv[j], acc, 0, 0, 0);
    }
    return acc;
}

// pack (col, col+1) bf16 pair into u32 and store via agent-scope (L2-bypassing) atomic
__device__ __forceinline__ void st_store(unsigned* st, int row, int colr, int lane, float v)
{
    float other = __shfl_xor(v, 1);
    if (!(lane & 1)) {
        unsigned lo = (unsigned)__bfloat16_as_ushort(__float2bfloat16(v));
        unsigned hi = (unsigned)__bfloat16_as_ushort(__float2bfloat16(other));
        __hip_atomic_store(st + ((row * 512 + colr) >> 1), lo | (hi << 16),
                           __ATOMIC_RELAXED, __HIP_MEMORY_SCOPE_AGENT);
    }
}

// stage the full 16x512 bf16 state into padded LDS [16][520] via u64 agent atomics
__device__ __forceinline__ void st_stage(unsigned short* ALds, const unsigned* st, int tid)
{
    const unsigned long long* st64 = (const unsigned long long*)st;
    for (int e = tid; e < 2048; e += 256) {
        unsigned long long uv = __hip_atomic_load(st64 + e, __ATOMIC_RELAXED, __HIP_MEMORY_SCOPE_AGENT);
        int row = e >> 7, cp = (e & 127) << 2;
        *(unsigned long long*)(ALds + row * 520 + cp) = uv;
    }
    __syncthreads();
}

// fence-free grid barrier: __syncthreads drains vmcnt (all sc1 stores acked)
__device__ __forceinline__ void gridbar(int* ctr, int* bar)
{
    __syncthreads();
    if (threadIdx.x == 0) {
        *bar += 8;
        __hip_atomic_fetch_add(ctr, 1, __ATOMIC_RELAXED, __HIP_MEMORY_SCOPE_AGENT);
        while (__hip_atomic_load(ctr, __ATOMIC_RELAXED, __HIP_MEMORY_SCOPE_AGENT) < *bar)
            __builtin_amdgcn_s_sleep(1);
    }
    __syncthreads();
}

// =====================================================================================
// Persistent head v3: weight prefetch hides load latency under barrier; u64 staging.
__global__ __launch_bounds__(256) void head3_kernel(
    const float* __restrict__ h,
    const bh16* __restrict__ mm1T, const float* __restrict__ mm1b,
    const bh16* __restrict__ mm2T, const float* __restrict__ mm2b,
    const bh16* __restrict__ dn1T,
    const bh16* __restrict__ dn2T, const float* __restrict__ dn2b,
    const bh16* __restrict__ dn3T, const float* __restrict__ dn3b,
    const bh16* __restrict__ outT, const float* __restrict__ outb,
    const float* __restrict__ pre1, const float* __restrict__ nsched,
    unsigned* __restrict__ stTM, unsigned* __restrict__ stCur,
    unsigned* __restrict__ stD1, unsigned* __restrict__ stD2,
    float* __restrict__ out, int* __restrict__ ctr)
{
    __shared__ __align__(16) unsigned short catL[16 * 1032];
    __shared__ __align__(16) unsigned short ALds[16 * 520];
    const int bx = blockIdx.x;
    const int tid = threadIdx.x;
    const int lane = tid & 63, w = tid >> 6;
    int bar = 0;
    const int col0 = bx * 64 + w * 16;
    const int colr = col0 + (lane & 15);
    const int row0 = (lane >> 4) * 4;
    bf16x8 bv[16];

    // build cat (16 x 1024) in LDS
    for (int e = tid; e < 16 * 1024; e += 256) {
        int k = e & 1023, b = e >> 10;
        float v = (k < 512) ? h[((size_t)b * TT + 255) * DD + k]
                            : h[((size_t)b * TT + 254) * DD + (k - 512)];
        catL[b * 1032 + k] = __bfloat16_as_ushort(__float2bfloat16(v));
    }
    __syncthreads();

    // mm1: tm = tanh(cat @ mm1T + b) -> stTM
    {
        f32x4 acc = lslice(catL, 1032, mm1T, 1024, col0, 1024, lane);
        float bs = mm1b[colr];
        #pragma unroll
        for (int r = 0; r < 4; ++r)
            st_store(stTM, row0 + r, colr, lane, tanhf(acc[r] + bs));
    }
    bload512(mm2T, 512, col0, lane, bv);     // prefetch mm2 under barrier
    gridbar(ctr, &bar);

    // mm2 + cur init
    float cur_reg[4];
    {
        st_stage(ALds, stTM, tid);
        f32x4 acc = lmfma512(ALds, 520, lane, bv);
        float bs = mm2b[colr];
        #pragma unroll
        for (int r = 0; r < 4; ++r) {
            float cv = h[((size_t)(row0 + r) * TT + 255) * DD + colr] + acc[r] + bs;
            cur_reg[r] = cv;
            st_store(stCur, row0 + r, colr, lane, cv);
        }
    }
    bload512(dn1T, 1024, col0, lane, bv);    // prefetch dn1 (cur part, K=0..511)
    gridbar(ctr, &bar);

    // diffusion chain
    for (int t = 0; t < SS; ++t) {
        float sc = nsched[t];
        {
            st_stage(ALds, stCur, tid);
            f32x4 acc = lmfma512(ALds, 520, lane, bv);
            #pragma unroll
            for (int r = 0; r < 4; ++r) {
                float v = acc[r] + pre1[(size_t)t * 8192 + (row0 + r) * 512 + colr];
                v = v / (1.f + expf(-v));
                st_store(stD1, row0 + r, colr, lane, v);
            }
        }
        bload512(dn2T, 512, col0, lane, bv);
        gridbar(ctr, &bar);
        {
            st_stage(ALds, stD1, tid);
            f32x4 acc = lmfma512(ALds, 520, lane, bv);
            float bs = dn2b[colr];
            #pragma unroll
            for (int r = 0; r < 4; ++r) {
                float v = acc[r] + bs;
                v = v / (1.f + expf(-v));
                st_store(stD2, row0 + r, colr, lane, v);
            }
        }
        bload512(dn3T, 512, col0, lane, bv);
        gridbar(ctr, &bar);
        {
            st_stage(ALds, stD2, tid);
            f32x4 acc = lmfma512(ALds, 520, lane, bv);
            float bs = dn3b[colr];
            #pragma unroll
            for (int r = 0; r < 4; ++r) {
                float nc = cur_reg[r] - (acc[r] + bs) * sc;
                cur_reg[r] = nc;
                st_store(stCur, row0 + r, colr, lane, nc);
            }
        }
        if (t < SS - 1) bload512(dn1T, 1024, col0, lane, bv);
        else if (bx < 6) bload512(outT, 512, col0, lane, bv);
        gridbar(ctr, &bar);
    }

    // out projection (N=384): blocks 0..5 store
    {
        st_stage(ALds, stCur, tid);
        if (bx < 6) {
            f32x4 acc = lmfma512(ALds, 520, lane, bv);
            float bs = outb[colr];
            #pragma unroll
            for (int r = 0; r < 4; ++r)
                out[(size_t)(row0 + r) * 384 + colr] = acc[r] + bs;
        }
    }
}

// ---------------- h = layernorm(s0+s1+s2+s3 + h)*g + b, dual fp32+bf16 out ----------------
__global__ __launch_bounds__(256) void add_ln_kernel(const float* __restrict__ s0, const float* __restrict__ s1,
                                                     const float* __restrict__ s2, const float* __restrict__ s3,
                                                     float* __restrict__ h, bh16* __restrict__ hb,
                                                     const float* __restrict__ g, const float* __restrict__ be)
{
    int lane = threadIdx.x & 63, wid = threadIdx.x >> 6;
    size_t row = (size_t)blockIdx.x * 4 + wid;
    const float* sr0 = s0 + row * DD;
    const float* sr1 = s1 + row * DD;
    const float* sr2 = s2 + row * DD;
    const float* sr3 = s3 + row * DD;
    float* hr = h + row * DD;
    bh16* hbr = hb + row * DD;
    float xv[8]; float sum = 0.f;
    #pragma unroll
    for (int u = 0; u < 8; ++u) {
        int c = lane + u * 64;
        xv[u] = sr0[c] + sr1[c] + sr2[c] + sr3[c] + hr[c];
        sum += xv[u];
    }
    #pragma unroll
    for (int off = 32; off; off >>= 1) sum += __shfl_xor(sum, off);
    float mu = sum * (1.f / 512.f);
    float sq = 0.f;
    #pragma unroll
    for (int u = 0; u < 8; ++u) { float d = xv[u] - mu; sq += d * d; }
    #pragma unroll
    for (int off = 32; off; off >>= 1) sq += __shfl_xor(sq, off);
    float rstd = 1.f / sqrtf(sq * (1.f / 512.f) + 1e-5f);
    #pragma unroll
    for (int u = 0; u < 8; ++u) {
        int c = lane + u * 64;
        float v = (xv[u] - mu) * rstd * g[c] + be[c];
        hr[c] = v;
        hbr[c] = __float2bfloat16(v);
    }
}

// ---------------- weight transpose-convert ----------------
__global__ __launch_bounds__(256) void wtrans_kernel(const float* __restrict__ W, bh16* __restrict__ Wt,
                                                     int K, int N, long lstride)
{
    int l = blockIdx.z;
    const float* Wl = W + (size_t)l * K * N;
    bh16* Wo = Wt + (size_t)l * lstride;
    __shared__ float tile[32][33];
    int n0 = blockIdx.x * 32, k0 = blockIdx.y * 32;
    int lx = threadIdx.x & 31, ly = threadIdx.x >> 5;
    #pragma unroll
    for (int j = 0; j < 4; ++j) {
        int kk = ly + j * 8;
        tile[kk][lx] = Wl[(size_t)(k0 + kk) * N + n0 + lx];
    }
    __syncthreads();
    #pragma unroll
    for (int j = 0; j < 4; ++j) {
        int nr = ly + j * 8;
        Wo[(size_t)(n0 + nr) * K + k0 + lx] = __float2bfloat16(tile[lx][nr]);
    }
}

// ---------------- fused qkv|te1 transpose: grid (50, 16, 6) ----------------
__global__ __launch_bounds__(256) void wtrans4_kernel(const float* __restrict__ gq, const float* __restrict__ gk,
                                                      const float* __restrict__ gv, const float* __restrict__ te1,
                                                      bh16* __restrict__ qkvT)
{
    int bxx = blockIdx.x, l = blockIdx.z;
    const float* W; long off; int N; int n0;
    if (bxx < 16)      { W = gq;  off = 0;      N = 512; n0 = bxx * 32; }
    else if (bxx < 32) { W = gk;  off = 262144; N = 512; n0 = (bxx - 16) * 32; }
    else if (bxx < 48) { W = gv;  off = 524288; N = 512; n0 = (bxx - 32) * 32; }
    else               { W = te1; off = 786432; N = 64;  n0 = (bxx - 48) * 32; }
    const float* Wl = W + (size_t)l * 512 * N;
    bh16* Wo = qkvT + (size_t)l * 819200 + off;
    __shared__ float tile[32][33];
    int k0 = blockIdx.y * 32;
    int lx = threadIdx.x & 31, ly = threadIdx.x >> 5;
    #pragma unroll
    for (int j = 0; j < 4; ++j) {
        int kk = ly + j * 8;
        tile[kk][lx] = Wl[(size_t)(k0 + kk) * N + n0 + lx];
    }
    __syncthreads();
    #pragma unroll
    for (int j = 0; j < 4; ++j) {
        int nr = ly + j * 8;
        Wo[(size_t)(n0 + nr) * 512 + k0 + lx] = __float2bfloat16(tile[lx][nr]);
    }
}

// ---------------- fused head weight transpose: 1984 blocks ----------------
__global__ __launch_bounds__(256) void wtransH_kernel(
    const float* __restrict__ mm1w, const float* __restrict__ mm2w,
    const float* __restrict__ dn1w, const float* __restrict__ dn2w,
    const float* __restrict__ dn3w, const float* __restrict__ outw,
    bh16* __restrict__ mm1T, bh16* __restrict__ mm2T, bh16* __restrict__ dn1T,
    bh16* __restrict__ dn2T, bh16* __restrict__ dn3T, bh16* __restrict__ outT)
{
    int bx = blockIdx.x;
    const float* W; bh16* Wo; int K, N, bloc;
    if (bx < 512)       { W = mm1w; Wo = mm1T; K = 1024; N = 512; bloc = bx; }
    else if (bx < 768)  { W = mm2w; Wo = mm2T; K = 512;  N = 512; bloc = bx - 512; }
    else if (bx < 1280) { W = dn1w; Wo = dn1T; K = 1024; N = 512; bloc = bx - 768; }
    else if (bx < 1536) { W = dn2w; Wo = dn2T; K = 512;  N = 512; bloc = bx - 1280; }
    else if (bx < 1792) { W = dn3w; Wo = dn3T; K = 512;  N = 512; bloc = bx - 1536; }
    else                { W = outw; Wo = outT; K = 512;  N = 384; bloc = bx - 1792; }
    int nblk = N / 32;
    int n0 = (bloc % nblk) * 32, k0 = (bloc / nblk) * 32;
    __shared__ float tile[32][33];
    int lx = threadIdx.x & 31, ly = threadIdx.x >> 5;
    #pragma unroll
    for (int j = 0; j < 4; ++j) {
        int kk = ly + j * 8;
        tile[kk][lx] = W[(size_t)(k0 + kk) * N + n0 + lx];
    }
    __syncthreads();
    #pragma unroll
    for (int j = 0; j < 4; ++j) {
        int nr = ly + j * 8;
        Wo[(size_t)(n0 + nr) * K + k0 + lx] = __float2bfloat16(tile[lx][nr]);
    }
}

// ---------------- cc_w [L][O][I][3] f32 -> ccT [L][O][tap*512+I] bf16 ----------------
__global__ __launch_bounds__(256) void ccconv_kernel(const float* __restrict__ ccw, bh16* __restrict__ ccT)
{
    size_t idx = (size_t)blockIdx.x * 256 + threadIdx.x;   // 6*512*1536
    int i = idx & 511; size_t rem = idx >> 9;
    int tap = (int)(rem % 3); rem /= 3;
    int o = (int)(rem & 511); int l = (int)(rem >> 9);
    ccT[idx] = __float2bfloat16(ccw[(((size_t)l*512 + o)*512 + i)*3 + tap]);
}

// ---------------- qkv|te1 bias concat [L][1600] + fused-epilogue bias sum [L][512] ----------------
__global__ __launch_bounds__(256) void qkvbias_kernel(const float* __restrict__ qb_, const float* __restrict__ kb_,
                                                      const float* __restrict__ vb_, const float* __restrict__ t1b_,
                                                      float* __restrict__ ob,
                                                      const float* __restrict__ gob, const float* __restrict__ wrb,
                                                      const float* __restrict__ tdb, const float* __restrict__ ccb,
                                                      float* __restrict__ bsum)
{
    int idx = blockIdx.x * 256 + threadIdx.x;
    if (idx < 6 * 1600) {
        int l = idx / 1600, n = idx % 1600;
        float v = (n < 512) ? qb_[l*512 + n]
                : (n < 1024) ? kb_[l*512 + n - 512]
                : (n < 1536) ? vb_[l*512 + n - 1024]
                : t1b_[l*64 + n - 1536];
        ob[idx] = v;
    }
    if (idx < 6 * 512) {
        bsum[idx] = gob[idx] + wrb[idx] + tdb[idx] + ccb[idx];
    }
}

// ---------------- x f32 -> bf16 ----------------
__global__ __launch_bounds__(256) void convx_kernel(const float* __restrict__ x, bh16* __restrict__ xb)
{
    size_t idx = (size_t)blockIdx.x * 256 + threadIdx.x;
    xb[idx] = __float2bfloat16(x[idx]);
}

// ---------------- E matrix: row (t,b) = [sched[t]*noise[t,b,:] | temb[t]] ----------------
__global__ __launch_bounds__(256) void build_E_kernel(const float* __restrict__ noise, const float* __restrict__ sched,
                                                      bh16* __restrict__ E)
{
    int idx = blockIdx.x * 256 + threadIdx.x;   // 10*16*1024
    if (idx >= SS * BB * 1024) return;
    int k = idx & 1023; int rem = idx >> 10; int b = rem & 15; int t = rem >> 4;
    float v;
    if (k < 512) {
        v = sched[t] * noise[((size_t)t * BB + b) * 512 + k];
    } else {
        int j = k - 512;
        const float kfac = -9.210340371976184f / 255.f;
        v = (j < 256) ? sinf((float)t * expf((float)j * kfac))
                      : cosf((float)t * expf((float)(j - 256) * kfac));
    }
    E[idx] = __float2bfloat16(v);
}

// ---------------- init: zero page, loss, grid-barrier counter ----------------
__global__ void init_kernel(bh16* zp, float* loss, int* ctr)
{
    int t = threadIdx.x;
    if (t < 64) zp[t] = __float2bfloat16(0.f);
    if (t == 64) *loss = 0.f;
    if (t == 65) *ctr = 0;
}

__global__ void fail_kernel(float* p) { p[0] = 1e30f; }

// =====================================================================================
extern "C" void kernel_launch(void* const* d_in, const int* in_sizes, int n_in,
                              void* d_out, int out_size, void* d_ws, size_t ws_size,
                              hipStream_t stream)
{
    const float* x      = (const float*)d_in[0];
    const float* in_w   = (const float*)d_in[1];
    const float* in_b   = (const float*)d_in[2];
    const float* gq_w   = (const float*)d_in[3];
    const float* gq_b   = (const float*)d_in[4];
    const float* gk_w   = (const float*)d_in[5];
    const float* gk_b   = (const float*)d_in[6];
    const float* gv_w   = (const float*)d_in[7];
    const float* gv_b   = (const float*)d_in[8];
    const float* go_w   = (const float*)d_in[9];
    const float* go_b   = (const float*)d_in[10];
    const float* curv   = (const float*)d_in[11];
    const float* wav0   = (const float*)d_in[12];
    const float* wav1   = (const float*)d_in[13];
    const float* wav2   = (const float*)d_in[14];
    const float* wav3   = (const float*)d_in[15];
    const float* wrec_w = (const float*)d_in[16];
    const float* wrec_b = (const float*)d_in[17];
    const float* te1_w  = (const float*)d_in[18];
    const float* te1_b  = (const float*)d_in[19];
    const float* te2_w  = (const float*)d_in[20];
    const float* te2_b  = (const float*)d_in[21];
    const float* td1_w  = (const float*)d_in[22];
    const float* td1_b  = (const float*)d_in[23];
    const float* td2_w  = (const float*)d_in[24];
    const float* td2_b  = (const float*)d_in[25];
    const float* bd_w   = (const float*)d_in[26];
    const float* bd_b   = (const float*)d_in[27];
    const float* cc_w   = (const float*)d_in[28];
    const float* cc_b   = (const float*)d_in[29];
    const float* ln_g   = (const float*)d_in[30];
    const float* ln_b   = (const float*)d_in[31];
    const float* mm1_w  = (const float*)d_in[32];
    const float* mm1_b  = (const float*)d_in[33];
    const float* mm2_w  = (const float*)d_in[34];
    const float* mm2_b  = (const float*)d_in[35];
    const float* dn1_w  = (const float*)d_in[36];
    const float* dn1_b  = (const float*)d_in[37];
    const float* dn2_w  = (const float*)d_in[38];
    const float* dn2_b  = (const float*)d_in[39];
    const float* dn3_w  = (const float*)d_in[40];
    const float* dn3_b  = (const float*)d_in[41];
    const float* out_w  = (const float*)d_in[42];
    const float* out_b  = (const float*)d_in[43];
    const float* nsched = (const float*)d_in[44];
    const float* noise  = (const float*)d_in[45];
    float* out = (float*)d_out;
    float* ws  = (float*)d_ws;

    // ---- fp32 workspace layout (float offsets) ----
    const size_t o_h   = 0;          // 2097152
    const size_t o_dec = 2097152;    // 2097152 (s2 partial; pre1 for head)
    const size_t o_s   = 4194304;    // 2097152
    const size_t o_at  = 6619136;    // 8388608: comb (bf16, first half) + s3/s4 partials
    const size_t o_qkb = 15054848;   // 9600
    const size_t o_bs  = 15064448;   // 3072
    const size_t o_ctr = 15067520;   // 1 (int)
    const size_t FP32_TOTAL = 15095808;
    // ---- bf16 region (element offsets from bp) ----
    const size_t b_xb   = 0;          // 1572864
    const size_t b_hb   = 1572864;    // 2097152
    const size_t b_qkv  = 3670016;    // 6553600: packed qkv|t1 [4096][1600]
    const size_t b_pb   = 12320768;   // 8388608 (head scratch region)
    const size_t b_gmb  = 20709376;   // 2097152
    const size_t b_tdb  = 22806528;   // 2097152
    const size_t b_zp   = 25165824;   // 512
    const size_t b_inwT = 25166336;   // 196608
    const size_t b_qkvT = 25362944;   // 4915200
    const size_t b_goT  = 30278144;   // 1572864
    const size_t b_wrT  = 31851008;   // 6291456
    const size_t b_td1T = 38142464;   // 196608
    const size_t b_td2T = 38339072;   // 1572864
    const size_t b_te2T = 39911936;   // 24576
    const size_t b_ccT  = 39936512;   // 4718592
    const size_t BF16_TOTAL = 44655104;
    const size_t TOTAL_BYTES = FP32_TOTAL * 4 + BF16_TOTAL * 2;
    if (ws_size < TOTAL_BYTES) { fail_kernel<<<1, 1, 0, stream>>>(out); return; }

    float* h_   = ws + o_h;
    float* s2_  = ws + o_dec;
    float* s_   = ws + o_s;
    float* at_  = ws + o_at;
    float* s3_  = at_ + 4194304;
    float* s4_  = at_ + 6291456;
    float* qkvbias = ws + o_qkb;
    float* bsum = ws + o_bs;
    int*   ctr  = (int*)(ws + o_ctr);
    bh16* bp   = (bh16*)(ws + FP32_TOTAL);
    bh16* xb   = bp + b_xb;
    bh16* hb   = bp + b_hb;
    bh16* qkvb = bp + b_qkv;
    bh16* pb   = bp + b_pb;
    bh16* gmb  = bp + b_gmb;
    bh16* tdb  = bp + b_tdb;
    bh16* zp   = bp + b_zp;
    bh16* inwT = bp + b_inwT;
    bh16* qkvT = bp + b_qkvT;
    bh16* goT  = bp + b_goT;
    bh16* wrT  = bp + b_wrT;
    bh16* td1T = bp + b_td1T;
    bh16* td2T = bp + b_td2T;
    bh16* te2T = bp + b_te2T;
    bh16* ccT  = bp + b_ccT;
    bh16* combb = (bh16*)at_;

    // head bf16 scratch: aliased into pb region (dead during layers)
    bh16* dn1T  = pb;             // 524288
    bh16* dn2T  = pb + 524288;    // 262144
    bh16* dn3T  = pb + 786432;    // 262144
    bh16* mm1T  = pb + 1048576;   // 524288
    bh16* mm2T  = pb + 1572864;   // 262144
    bh16* outT  = pb + 1835008;   // 196608
    bh16* E16   = pb + 2031616;   // 163840
    float* pre1 = s2_;            // 81920 f32, aliases s2 after layers
    // head state (u32-packed bf16, agent-scope atomics): in s4_ area
    unsigned* stTM  = (unsigned*)s4_;          // 4096 u32 each
    unsigned* stCur = stTM + 4096;
    unsigned* stD1  = stTM + 8192;
    unsigned* stD2  = stTM + 12288;

    auto mgp = [&](const bh16* A, int lda, const bh16* Bt, int ldb,
                   const float* bias, float* Cf, bh16* Cb, int ldc,
                   int M, int N, int K, int shift, int accum, int act) {
        dim3 g((N + 63) / 64, M / 128, 1);
        mgemm_kernel<<<g, 256, 0, stream>>>(A, lda, Bt, ldb, bias, Cf, Cb, ldc, N, K,
                                            shift, accum, act, zp);
    };

    // ---- setup ----
    init_kernel<<<1, 128, 0, stream>>>(zp, out + BB * DIN, ctr);
    convx_kernel<<<BT * DIN / 256, 256, 0, stream>>>(x, xb);
    wtrans_kernel<<<dim3(DD/32, DIN/32, 1), 256, 0, stream>>>(in_w, inwT, DIN, DD, (long)DIN*DD);
    wtrans4_kernel<<<dim3(50, 16, 6), 256, 0, stream>>>(gq_w, gk_w, gv_w, te1_w, qkvT);
    qkvbias_kernel<<<38, 256, 0, stream>>>(gq_b, gk_b, gv_b, te1_b, qkvbias,
                                           go_b, wrec_b, td2_b, cc_b, bsum);
    wtrans_kernel<<<dim3(16, 16, 6), 256, 0, stream>>>(go_w, goT, DD, DD, (long)DD*DD);
    wtrans_kernel<<<dim3(16, 64, 6), 256, 0, stream>>>(wrec_w, wrT, 2048, DD, 2048L*DD);
    wtrans_kernel<<<dim3(16, 2, 6), 256, 0, stream>>>(td1_w, td1T, PP, DD, (long)PP*DD);
    wtrans_kernel<<<dim3(16, 16, 6), 256, 0, stream>>>(td2_w, td2T, DD, DD, (long)DD*DD);
    wtrans_kernel<<<dim3(2, 2, 6), 256, 0, stream>>>(te2_w, te2T, PP, PP, (long)PP*PP);
    ccconv_kernel<<<18432, 256, 0, stream>>>(cc_w, ccT);

    // h = x @ in_w + in_b  (fp32 + bf16)
    mgp(xb, DIN, inwT, DIN, in_b, h_, hb, DD, BT, DD, DIN, 0, 0, ACT_NONE);

    for (int l = 0; l < LL; ++l) {
        mgp(hb, DD, qkvT + (size_t)l*819200, DD, qkvbias + (size_t)l*1600,
            nullptr, qkvb, 1600, BT, 1600, DD, 0, 0, ACT_RELU_TAIL);
        fattn_kernel<<<dim3(4, 128), 256, 0, stream>>>(qkvb, curv + (size_t)l*HH, gmb);
        // merged wavelet + topo (independent after qkv)
        midwt_kernel<<<1280, 256, 0, stream>>>(
            hb, wav0, wav1, wav2, wav3, l, combb,
            qkvb + 1536, te2T + (size_t)l*4096, te2_b + (size_t)l*PP,
            td1T + (size_t)l*32768, td1_b + (size_t)l*DD,
            bd_w + (size_t)l*PP*2, bd_b + (size_t)l*2, out + BB*DIN, tdb);
        fgemm_kernel<<<dim3(8, 32, 4), 256, 0, stream>>>(
            gmb, combb, tdb, hb,
            goT + (size_t)l*262144, wrT + (size_t)l*1048576,
            td2T + (size_t)l*262144, ccT + (size_t)l*786432,
            bsum + (size_t)l*512, s_, s2_, s3_, s4_, 1 << l, zp);
        add_ln_kernel<<<BT/4, 256, 0, stream>>>(s_, s2_, s3_, s4_, h_, hb, ln_g, ln_b);
    }

    // ---- head ----
    wtransH_kernel<<<1984, 256, 0, stream>>>(mm1_w, mm2_w, dn1_w, dn2_w, dn3_w, out_w,
                                             mm1T, mm2T, dn1T, dn2T, dn3T, outT);
    build_E_kernel<<<640, 256, 0, stream>>>(noise, nsched, E16);
    hgemm16_kernel<<<dim3(8, 1, SS), 256, 0, stream>>>(
        E16, 1024, 16*1024, dn1T, 1024, dn1_b, nullptr, pre1, nullptr, 8192,
        512, 1024, ACT_NONE, nullptr, nullptr, nullptr);
    head3_kernel<<<8, 256, 0, stream>>>(
        h_, mm1T, mm1_b, mm2T, mm2_b, dn1T, dn2T, dn2_b, dn3T, dn3_b,
        outT, out_b, pre1, nsched, stTM, stCur, stD1, stD2, out, ctr);
}

// Round 18
// 950.135 us; speedup vs baseline: 1.0618x; 1.0618x over previous
//
#include <hip/hip_runtime.h>
#include <hip/hip_bf16.h>
#include <math.h>

#define BB 16
#define TT 256
#define DIN 384
#define DD 512
#define LL 6
#define HH 8
#define PP 64
#define SS 10
#define BT (BB*TT)   // 4096

enum { ACT_NONE=0, ACT_RELU=1, ACT_TANH=2, ACT_SILU=3, ACT_RELU_TAIL=4 };

typedef __attribute__((ext_vector_type(8))) short bf16x8;
typedef __attribute__((ext_vector_type(4))) float f32x4;
typedef __hip_bfloat16 bh16;

typedef const __attribute__((address_space(1))) void gvoid_t;
typedef __attribute__((address_space(3))) void lvoid_t;
__device__ __forceinline__ void gload16(const void* g, void* l) {
    __builtin_amdgcn_global_load_lds((gvoid_t*)g, (lvoid_t*)l, 16, 0, 0);
}

__device__ __forceinline__ float b2f(unsigned short u) {
    return __uint_as_float(((unsigned int)u) << 16);
}

// bijective chunked XCD swizzle (m204) within one z-plane.
__device__ __forceinline__ void xcd_swizzle_always(int& bx, int& by) {
    int gx = gridDim.x;
    int nwg = gx * gridDim.y;
    int lid = by * gx + bx;
    int q = nwg >> 3, r = nwg & 7;
    int xcd = lid & 7, idx = lid >> 3;
    int swz = (xcd < r) ? (xcd * (q + 1) + idx) : (r * (q + 1) + (xcd - r) * q + idx);
    bx = swz % gx;
    by = swz / gx;
}
__device__ __forceinline__ void xcd_swizzle(int& bx, int& by) {
    if (gridDim.z == 1) xcd_swizzle_always(bx, by);
}

// =====================================================================================
// Generic bf16 MFMA GEMM: C = act(A @ Bt^T + bias)  (Bt stored [N][K])
__global__ __launch_bounds__(256) void mgemm_kernel(
    const bh16* __restrict__ A, int lda,
    const bh16* __restrict__ Bt, int ldb,
    const float* __restrict__ bias,
    float* __restrict__ Cf, bh16* __restrict__ Cb, int ldc,
    int N, int K, int shift, int accum, int act,
    const bh16* __restrict__ zp)
{
    __shared__ bf16x8 As[128*8];
    __shared__ bf16x8 Bs[64*8];

    int bx = blockIdx.x, by = blockIdx.y;
    xcd_swizzle(bx, by);

    const int tid  = threadIdx.x;
    const int lane = tid & 63, w = tid >> 6;
    const int wm = w >> 1, wn = w & 1;
    const int row0 = by * 128, col0 = bx * 64;

    f32x4 acc[4][2];
    #pragma unroll
    for (int i = 0; i < 4; ++i)
        #pragma unroll
        for (int j = 0; j < 2; ++j) acc[i][j] = (f32x4){0.f,0.f,0.f,0.f};

    const int nkt = K >> 6;
    for (int kt = 0; kt < nkt; ++kt) {
        int k0 = kt << 6;
        #pragma unroll
        for (int j = 0; j < 4; ++j) {
            int c = ((w*4 + j) << 6) + lane;
            int row = c >> 3, chk = c & 7;
            int schk = chk ^ (row & 7);
            int grow = row0 + row;
            const bh16* src = ((grow & 255) >= shift)
                ? (A + (size_t)(grow - shift)*lda + k0 + schk*8) : zp;
            gload16(src, &As[(w*4 + j) * 64]);
        }
        #pragma unroll
        for (int j = 0; j < 2; ++j) {
            int c = ((w*2 + j) << 6) + lane;
            int row = c >> 3, chk = c & 7;
            int schk = chk ^ (row & 7);
            int gcol = col0 + row;
            const bh16* src = (gcol < N)
                ? (Bt + (size_t)gcol*ldb + k0 + schk*8) : zp;
            gload16(src, &Bs[(w*2 + j) * 64]);
        }
        asm volatile("s_waitcnt vmcnt(0)" ::: "memory");
        __syncthreads();

        bf16x8 a[4][2], b[2][2];
        #pragma unroll
        for (int fm = 0; fm < 4; ++fm) {
            int row = wm*64 + fm*16 + (lane & 15);
            #pragma unroll
            for (int ks = 0; ks < 2; ++ks)
                a[fm][ks] = As[row*8 + ((ks*4 + (lane>>4)) ^ (row & 7))];
        }
        #pragma unroll
        for (int fn = 0; fn < 2; ++fn) {
            int col = wn*32 + fn*16 + (lane & 15);
            #pragma unroll
            for (int ks = 0; ks < 2; ++ks)
                b[fn][ks] = Bs[col*8 + ((ks*4 + (lane>>4)) ^ (col & 7))];
        }
        #pragma unroll
        for (int ks = 0; ks < 2; ++ks)
            #pragma unroll
            for (int fm = 0; fm < 4; ++fm)
                #pragma unroll
                for (int fn = 0; fn < 2; ++fn)
                    acc[fm][fn] = __builtin_amdgcn_mfma_f32_16x16x32_bf16(
                        a[fm][ks], b[fn][ks], acc[fm][fn], 0, 0, 0);
        __syncthreads();
    }

    #pragma unroll
    for (int fm = 0; fm < 4; ++fm) {
        #pragma unroll
        for (int fn = 0; fn < 2; ++fn) {
            int gc = col0 + wn*32 + fn*16 + (lane & 15);
            float bs = bias ? bias[gc] : 0.f;
            #pragma unroll
            for (int r = 0; r < 4; ++r) {
                int gr = row0 + wm*64 + fm*16 + (lane>>4)*4 + r;
                float v = acc[fm][fn][r] + bs;
                if (act == ACT_RELU) v = fmaxf(v, 0.f);
                else if (act == ACT_RELU_TAIL && gc >= 1536) v = fmaxf(v, 0.f);
                size_t o = (size_t)gr*ldc + gc;
                if (Cf) { if (accum) Cf[o] += v; else Cf[o] = v; }
                if (Cb) Cb[o] = __float2bfloat16(v);
            }
        }
    }
}

// =====================================================================================
// Fused topo: tf = t1@te2 + b, bd loss (bx==0), tdb = relu(tf@td1 + b). grid (8, 32).
__global__ __launch_bounds__(256) void topo_kernel(
    const bh16* __restrict__ t1,     // qkvb+1536, lda 1600
    const bh16* __restrict__ te2T,   // [64][64]
    const float* __restrict__ te2b,
    const bh16* __restrict__ td1T,   // [512][64]
    const float* __restrict__ td1b,
    const float* __restrict__ bdw, const float* __restrict__ bdb,
    float* __restrict__ loss,
    bh16* __restrict__ tdb)          // [4096][512]
{
    __shared__ bf16x8 As[128*8];
    __shared__ bf16x8 Bs[64*8];
    __shared__ float redT[2][128];
    __shared__ float bsumS;

    const int bx = blockIdx.x, by = blockIdx.y;
    const int lane = threadIdx.x & 63, w = threadIdx.x >> 6;
    const int wm = w >> 1, wn = w & 1;
    const int row0 = by * 128;

    #pragma unroll
    for (int j = 0; j < 4; ++j) {
        int c = ((w*4 + j) << 6) + lane;
        int row = c >> 3, chk = c & 7, schk = chk ^ (row & 7);
        gload16(t1 + (size_t)(row0 + row)*1600 + schk*8, &As[(w*4+j)*64]);
    }
    #pragma unroll
    for (int j = 0; j < 2; ++j) {
        int c = ((w*2 + j) << 6) + lane;
        int row = c >> 3, chk = c & 7, schk = chk ^ (row & 7);
        gload16(te2T + (size_t)row*64 + schk*8, &Bs[(w*2+j)*64]);
    }
    asm volatile("s_waitcnt vmcnt(0)" ::: "memory");
    __syncthreads();

    f32x4 acc[4][2];
    #pragma unroll
    for (int i = 0; i < 4; ++i)
        #pragma unroll
        for (int j = 0; j < 2; ++j) acc[i][j] = (f32x4){0.f,0.f,0.f,0.f};
    {
        bf16x8 a[4][2], b[2][2];
        #pragma unroll
        for (int fm = 0; fm < 4; ++fm) {
            int row = wm*64 + fm*16 + (lane & 15);
            #pragma unroll
            for (int ks = 0; ks < 2; ++ks)
                a[fm][ks] = As[row*8 + ((ks*4 + (lane>>4)) ^ (row & 7))];
        }
        #pragma unroll
        for (int fn = 0; fn < 2; ++fn) {
            int col = wn*32 + fn*16 + (lane & 15);
            #pragma unroll
            for (int ks = 0; ks < 2; ++ks)
                b[fn][ks] = Bs[col*8 + ((ks*4 + (lane>>4)) ^ (col & 7))];
        }
        #pragma unroll
        for (int ks = 0; ks < 2; ++ks)
            #pragma unroll
            for (int fm = 0; fm < 4; ++fm)
                #pragma unroll
                for (int fn = 0; fn < 2; ++fn)
                    acc[fm][fn] = __builtin_amdgcn_mfma_f32_16x16x32_bf16(
                        a[fm][ks], b[fn][ks], acc[fm][fn], 0, 0, 0);
    }
    #pragma unroll
    for (int fn = 0; fn < 2; ++fn) {
        int gc = wn*32 + fn*16 + (lane & 15);
        float bs = te2b[gc];
        #pragma unroll
        for (int fm = 0; fm < 4; ++fm)
            #pragma unroll
            for (int r = 0; r < 4; ++r) acc[fm][fn][r] += bs;
    }

    if (bx == 0) {
        float bconst = (bdb[0] - bdb[1]) + 0.1f;
        float wv[2];
        #pragma unroll
        for (int fn = 0; fn < 2; ++fn) {
            int gc = wn*32 + fn*16 + (lane & 15);
            wv[fn] = bdw[gc*2] - bdw[gc*2 + 1];
        }
        float dp[4][4];
        #pragma unroll
        for (int fm = 0; fm < 4; ++fm)
            #pragma unroll
            for (int r = 0; r < 4; ++r) {
                dp[fm][r] = acc[fm][0][r]*wv[0] + acc[fm][1][r]*wv[1];
                #pragma unroll
                for (int off = 1; off < 16; off <<= 1)
                    dp[fm][r] += __shfl_xor(dp[fm][r], off);
            }
        if ((lane & 15) == 0)
            #pragma unroll
            for (int fm = 0; fm < 4; ++fm)
                #pragma unroll
                for (int r = 0; r < 4; ++r)
                    redT[wn][wm*64 + fm*16 + (lane>>4)*4 + r] = dp[fm][r];
        if (threadIdx.x == 0) bsumS = 0.f;
        __syncthreads();
        if (wn == 0 && (lane & 15) == 0) {
            float ls = 0.f;
            #pragma unroll
            for (int fm = 0; fm < 4; ++fm)
                #pragma unroll
                for (int r = 0; r < 4; ++r) {
                    int rowl = wm*64 + fm*16 + (lane>>4)*4 + r;
                    ls += fmaxf(dp[fm][r] + redT[1][rowl] + bconst, 0.f);
                }
            atomicAdd(&bsumS, ls);
        }
        __syncthreads();
        if (threadIdx.x == 0) atomicAdd(loss, bsumS * (1.f / 4096.f));
    }

    __syncthreads();
    #pragma unroll
    for (int fm = 0; fm < 4; ++fm)
        #pragma unroll
        for (int fn = 0; fn < 2; ++fn)
            #pragma unroll
            for (int r = 0; r < 4; ++r) {
                int rowl = wm*64 + fm*16 + (lane>>4)*4 + r;
                int gc = wn*32 + fn*16 + (lane & 15);
                ((bh16*)As)[(rowl*8 + ((gc >> 3) ^ (rowl & 7)))*8 + (gc & 7)] =
                    __float2bfloat16(acc[fm][fn][r]);
            }
    #pragma unroll
    for (int j = 0; j < 2; ++j) {
        int c = ((w*2 + j) << 6) + lane;
        int row = c >> 3, chk = c & 7, schk = chk ^ (row & 7);
        gload16(td1T + (size_t)(bx*64 + row)*64 + schk*8, &Bs[(w*2+j)*64]);
    }
    asm volatile("s_waitcnt vmcnt(0)" ::: "memory");
    __syncthreads();

    f32x4 acc2[4][2];
    #pragma unroll
    for (int i = 0; i < 4; ++i)
        #pragma unroll
        for (int j = 0; j < 2; ++j) acc2[i][j] = (f32x4){0.f,0.f,0.f,0.f};
    {
        bf16x8 a[4][2], b[2][2];
        #pragma unroll
        for (int fm = 0; fm < 4; ++fm) {
            int row = wm*64 + fm*16 + (lane & 15);
            #pragma unroll
            for (int ks = 0; ks < 2; ++ks)
                a[fm][ks] = As[row*8 + ((ks*4 + (lane>>4)) ^ (row & 7))];
        }
        #pragma unroll
        for (int fn = 0; fn < 2; ++fn) {
            int col = wn*32 + fn*16 + (lane & 15);
            #pragma unroll
            for (int ks = 0; ks < 2; ++ks)
                b[fn][ks] = Bs[col*8 + ((ks*4 + (lane>>4)) ^ (col & 7))];
        }
        #pragma unroll
        for (int ks = 0; ks < 2; ++ks)
            #pragma unroll
            for (int fm = 0; fm < 4; ++fm)
                #pragma unroll
                for (int fn = 0; fn < 2; ++fn)
                    acc2[fm][fn] = __builtin_amdgcn_mfma_f32_16x16x32_bf16(
                        a[fm][ks], b[fn][ks], acc2[fm][fn], 0, 0, 0);
    }
    #pragma unroll
    for (int fm = 0; fm < 4; ++fm)
        #pragma unroll
        for (int fn = 0; fn < 2; ++fn) {
            int gcol = bx*64 + wn*32 + fn*16 + (lane & 15);
            float bs = td1b[gcol];
            #pragma unroll
            for (int r = 0; r < 4; ++r) {
                int gr = row0 + wm*64 + fm*16 + (lane>>4)*4 + r;
                tdb[(size_t)gr*512 + gcol] = __float2bfloat16(fmaxf(acc2[fm][fn][r] + bs, 0.f));
            }
        }
}

// =====================================================================================
// Fused attention: norms + QK^T + hyperbolic softmax + V-transpose + PV, one kernel.
__global__ __launch_bounds__(256) void fattn_kernel(
    const bh16* __restrict__ qkv,      // [4096][1600]: q@0, k@+512, v@+1024
    const float* __restrict__ curv,
    bh16* __restrict__ gmb)            // [4096][512]
{
    __shared__ bf16x8 Qs[64*8];
    __shared__ bf16x8 Ks[256*8];
    __shared__ __align__(16) bh16 Ps[64*64];
    __shared__ bf16x8 Bv[64*8];
    __shared__ unsigned short Vst[64*72];
    __shared__ float redA[2][64];
    __shared__ float redB[2][64];
    __shared__ float qnS[64];
    __shared__ float knS[256];

    const int rh = blockIdx.x;
    const int bh = blockIdx.y;
    const int b = bh >> 3, hh = bh & 7;
    const int lane = threadIdx.x & 63, w = threadIdx.x >> 6;
    const int wm = w >> 1, wn = w & 1;

    const bh16* qbase = qkv + hh * 64;
    const bh16* kbase = qkv + 512 + hh * 64;
    #pragma unroll
    for (int j = 0; j < 2; ++j) {
        int c = ((w*2 + j) << 6) + lane;
        int row = c >> 3, chk = c & 7, schk = chk ^ (row & 7);
        gload16(qbase + (size_t)(b*256 + rh*64 + row)*1600 + schk*8, &Qs[(w*2+j)*64]);
    }
    #pragma unroll
    for (int j = 0; j < 8; ++j) {
        int c = ((w*8 + j) << 6) + lane;
        int row = c >> 3, chk = c & 7, schk = chk ^ (row & 7);
        gload16(kbase + (size_t)(b*256 + row)*1600 + schk*8, &Ks[(w*8+j)*64]);
    }
    asm volatile("s_waitcnt vmcnt(0)" ::: "memory");
    __syncthreads();

    {
        int t = threadIdx.x;
        float s = 0.f;
        #pragma unroll
        for (int jj = 0; jj < 8; ++jj) {
            bf16x8 v = Ks[t*8 + ((t + jj) & 7)];
            #pragma unroll
            for (int e = 0; e < 8; ++e) { float f = b2f((unsigned short)v[e]); s += f * f; }
        }
        knS[t] = s;
        if (t < 64) {
            float sq = 0.f;
            #pragma unroll
            for (int jj = 0; jj < 8; ++jj) {
                bf16x8 v = Qs[t*8 + ((t + jj) & 7)];
                #pragma unroll
                for (int e = 0; e < 8; ++e) { float f = b2f((unsigned short)v[e]); sq += f * f; }
            }
            qnS[t] = sq;
        }
    }
    __syncthreads();

    f32x4 acc[2][8];
    #pragma unroll
    for (int i = 0; i < 2; ++i)
        #pragma unroll
        for (int j = 0; j < 8; ++j) acc[i][j] = (f32x4){0.f,0.f,0.f,0.f};

    bf16x8 af[2][2];
    #pragma unroll
    for (int fm = 0; fm < 2; ++fm) {
        int row = wm*32 + fm*16 + (lane & 15);
        #pragma unroll
        for (int ks = 0; ks < 2; ++ks)
            af[fm][ks] = Qs[row*8 + ((ks*4 + (lane>>4)) ^ (row & 7))];
    }
    #pragma unroll
    for (int fn = 0; fn < 8; ++fn) {
        int col = wn*128 + fn*16 + (lane & 15);
        #pragma unroll
        for (int ks = 0; ks < 2; ++ks) {
            bf16x8 bf = Ks[col*8 + ((ks*4 + (lane>>4)) ^ (col & 7))];
            #pragma unroll
            for (int fm = 0; fm < 2; ++fm)
                acc[fm][fn] = __builtin_amdgcn_mfma_f32_16x16x32_bf16(
                    af[fm][ks], bf, acc[fm][fn], 0, 0, 0);
        }
    }

    const float c_ = fabsf(curv[hh]) + 1e-8f;
    const float isc = 1.f / sqrtf(c_);
    float qnv[2][4], knv[8];
    #pragma unroll
    for (int fm = 0; fm < 2; ++fm)
        #pragma unroll
        for (int r = 0; r < 4; ++r)
            qnv[fm][r] = qnS[wm*32 + fm*16 + (lane>>4)*4 + r];
    #pragma unroll
    for (int fn = 0; fn < 8; ++fn)
        knv[fn] = knS[wn*128 + fn*16 + (lane & 15)];

    float rmax[2][4];
    #pragma unroll
    for (int fm = 0; fm < 2; ++fm)
        #pragma unroll
        for (int r = 0; r < 4; ++r) rmax[fm][r] = -1e30f;
    #pragma unroll
    for (int fm = 0; fm < 2; ++fm)
        #pragma unroll
        for (int fn = 0; fn < 8; ++fn)
            #pragma unroll
            for (int r = 0; r < 4; ++r) {
                float s = acc[fm][fn][r];
                float d2 = fmaxf(qnv[fm][r] + knv[fn] - 2.f * s, 0.f);
                float denom = fmaxf((1.f - c_ * qnv[fm][r]) * (1.f - c_ * knv[fn]), 1e-5f);
                float arg = fmaxf(1.f + (2.f * c_ * d2) / denom, 1.00001f);
                float dist = logf(arg + sqrtf((arg - 1.f) * (arg + 1.f))) * isc;
                float lg = -dist;
                acc[fm][fn][r] = lg;
                rmax[fm][r] = fmaxf(rmax[fm][r], lg);
            }
    #pragma unroll
    for (int off = 1; off < 16; off <<= 1)
        #pragma unroll
        for (int fm = 0; fm < 2; ++fm)
            #pragma unroll
            for (int r = 0; r < 4; ++r)
                rmax[fm][r] = fmaxf(rmax[fm][r], __shfl_xor(rmax[fm][r], off));
    if ((lane & 15) == 0)
        #pragma unroll
        for (int fm = 0; fm < 2; ++fm)
            #pragma unroll
            for (int r = 0; r < 4; ++r)
                redA[wn][wm*32 + fm*16 + (lane>>4)*4 + r] = rmax[fm][r];
    __syncthreads();
    #pragma unroll
    for (int fm = 0; fm < 2; ++fm)
        #pragma unroll
        for (int r = 0; r < 4; ++r)
            rmax[fm][r] = fmaxf(rmax[fm][r], redA[wn ^ 1][wm*32 + fm*16 + (lane>>4)*4 + r]);
    float rsum[2][4];
    #pragma unroll
    for (int fm = 0; fm < 2; ++fm)
        #pragma unroll
        for (int r = 0; r < 4; ++r) rsum[fm][r] = 0.f;
    #pragma unroll
    for (int fm = 0; fm < 2; ++fm)
        #pragma unroll
        for (int fn = 0; fn < 8; ++fn)
            #pragma unroll
            for (int r = 0; r < 4; ++r) {
                float e = expf(acc[fm][fn][r] - rmax[fm][r]);
                acc[fm][fn][r] = e;
                rsum[fm][r] += e;
            }
    #pragma unroll
    for (int off = 1; off < 16; off <<= 1)
        #pragma unroll
        for (int fm = 0; fm < 2; ++fm)
            #pragma unroll
            for (int r = 0; r < 4; ++r)
                rsum[fm][r] += __shfl_xor(rsum[fm][r], off);
    if ((lane & 15) == 0)
        #pragma unroll
        for (int fm = 0; fm < 2; ++fm)
            #pragma unroll
            for (int r = 0; r < 4; ++r)
                redB[wn][wm*32 + fm*16 + (lane>>4)*4 + r] = rsum[fm][r];
    __syncthreads();
    float pinv[2][4];
    #pragma unroll
    for (int fm = 0; fm < 2; ++fm)
        #pragma unroll
        for (int r = 0; r < 4; ++r)
            pinv[fm][r] = 1.f / (rsum[fm][r] + redB[wn ^ 1][wm*32 + fm*16 + (lane>>4)*4 + r]);

    f32x4 acc2[2][2];
    #pragma unroll
    for (int i = 0; i < 2; ++i)
        #pragma unroll
        for (int j = 0; j < 2; ++j) acc2[i][j] = (f32x4){0.f,0.f,0.f,0.f};

    const bh16* vbase = qkv + 1024 + hh * 64;
    for (int kt = 0; kt < 4; ++kt) {
        __syncthreads();
        if (wn == (kt >> 1)) {
            int fnb = (kt & 1) * 4;
            #pragma unroll
            for (int fm = 0; fm < 2; ++fm)
                #pragma unroll
                for (int fnl = 0; fnl < 4; ++fnl)
                    #pragma unroll
                    for (int r = 0; r < 4; ++r) {
                        int rowl = wm*32 + fm*16 + (lane>>4)*4 + r;
                        int kl = fnl*16 + (lane & 15);
                        float p = acc[fm][fnb + fnl][r] * pinv[fm][r];
                        Ps[(rowl*8 + ((kl >> 3) ^ (rowl & 7)))*8 + (kl & 7)] = __float2bfloat16(p);
                    }
        }
        #pragma unroll
        for (int j = 0; j < 2; ++j) {
            int c = threadIdx.x + j*256;
            int tr = c >> 3, chk = c & 7;
            bf16x8 v = *(const bf16x8*)(vbase + (size_t)(b*256 + kt*64 + tr)*1600 + chk*8);
            *(bf16x8*)(&Vst[tr*72 + chk*8]) = v;
        }
        __syncthreads();
        #pragma unroll
        for (int j = 0; j < 2; ++j) {
            int c = threadIdx.x + j*256;
            int col = c & 63, chk = c >> 6;
            bf16x8 v;
            #pragma unroll
            for (int e = 0; e < 8; ++e)
                v[e] = (short)Vst[(chk*8 + e)*72 + col];
            Bv[col*8 + (chk ^ (col & 7))] = v;
        }
        __syncthreads();

        bf16x8 pa[2][2], vb[2][2];
        #pragma unroll
        for (int fm = 0; fm < 2; ++fm) {
            int row = wm*32 + fm*16 + (lane & 15);
            #pragma unroll
            for (int ks = 0; ks < 2; ++ks)
                pa[fm][ks] = ((bf16x8*)Ps)[row*8 + ((ks*4 + (lane>>4)) ^ (row & 7))];
        }
        #pragma unroll
        for (int fn = 0; fn < 2; ++fn) {
            int col = wn*32 + fn*16 + (lane & 15);
            #pragma unroll
            for (int ks = 0; ks < 2; ++ks)
                vb[fn][ks] = Bv[col*8 + ((ks*4 + (lane>>4)) ^ (col & 7))];
        }
        #pragma unroll
        for (int ks = 0; ks < 2; ++ks)
            #pragma unroll
            for (int fm = 0; fm < 2; ++fm)
                #pragma unroll
                for (int fn = 0; fn < 2; ++fn)
                    acc2[fm][fn] = __builtin_amdgcn_mfma_f32_16x16x32_bf16(
                        pa[fm][ks], vb[fn][ks], acc2[fm][fn], 0, 0, 0);
    }

    #pragma unroll
    for (int fm = 0; fm < 2; ++fm)
        #pragma unroll
        for (int fn = 0; fn < 2; ++fn)
            #pragma unroll
            for (int r = 0; r < 4; ++r) {
                int rowl = wm*32 + fm*16 + (lane>>4)*4 + r;
                int col = wn*32 + fn*16 + (lane & 15);
                gmb[((size_t)(b*256 + rh*64 + rowl))*512 + hh*64 + col] =
                    __float2bfloat16(acc2[fm][fn][r]);
            }
}

// =====================================================================================
// Fused 4-segment GEMM, split-K=4 over blockIdx.z (18 kt each)
__global__ __launch_bounds__(256) void fgemm_kernel(
    const bh16* __restrict__ A0, const bh16* __restrict__ A1,
    const bh16* __restrict__ A2, const bh16* __restrict__ A3,
    const bh16* __restrict__ B0, const bh16* __restrict__ B1,
    const bh16* __restrict__ B2, const bh16* __restrict__ B3,
    const float* __restrict__ bias,
    float* __restrict__ Cf0, float* __restrict__ Cf1,
    float* __restrict__ Cf2, float* __restrict__ Cf3,
    int dil, const bh16* __restrict__ zp)
{
    __shared__ bf16x8 As[128*8];
    __shared__ bf16x8 Bs[64*8];

    int bx = blockIdx.x, by = blockIdx.y;
    xcd_swizzle_always(bx, by);
    const int zz = blockIdx.z;
    const int ktlo = zz * 18;
    const int kthi = ktlo + 18;

    const int tid  = threadIdx.x;
    const int lane = tid & 63, w = tid >> 6;
    const int wm = w >> 1, wn = w & 1;
    const int row0 = by * 128, col0 = bx * 64;

    f32x4 acc[4][2];
    #pragma unroll
    for (int i = 0; i < 4; ++i)
        #pragma unroll
        for (int j = 0; j < 2; ++j) acc[i][j] = (f32x4){0.f,0.f,0.f,0.f};

    for (int kt = ktlo; kt < kthi; ++kt) {
        const bh16* Aseg; const bh16* Bseg;
        int ldas, ldbs, k0, mask_sh, addr_sh;
        if (kt < 8) {
            Aseg = A0; Bseg = B0; ldas = 512; ldbs = 512;
            k0 = kt << 6; mask_sh = 0; addr_sh = 0;
        } else if (kt < 40) {
            Aseg = A1; Bseg = B1; ldas = 2048; ldbs = 2048;
            k0 = (kt - 8) << 6; mask_sh = 0; addr_sh = 0;
        } else if (kt < 48) {
            Aseg = A2; Bseg = B2; ldas = 512; ldbs = 512;
            k0 = (kt - 40) << 6; mask_sh = 0; addr_sh = 0;
        } else {
            int kl = kt - 48, tap = kl >> 3;
            Aseg = A3; Bseg = B3; ldas = 512; ldbs = 1536;
            k0 = kl << 6;
            mask_sh = (2 - tap) * dil;
            addr_sh = mask_sh + tap;
        }
        #pragma unroll
        for (int j = 0; j < 4; ++j) {
            int c = ((w*4 + j) << 6) + lane;
            int row = c >> 3, chk = c & 7;
            int schk = chk ^ (row & 7);
            int grow = row0 + row;
            const bh16* src = ((grow & 255) >= mask_sh)
                ? (Aseg + (size_t)(grow - addr_sh)*ldas + k0 + schk*8) : zp;
            gload16(src, &As[(w*4 + j) * 64]);
        }
        #pragma unroll
        for (int j = 0; j < 2; ++j) {
            int c = ((w*2 + j) << 6) + lane;
            int row = c >> 3, chk = c & 7;
            int schk = chk ^ (row & 7);
            int gcol = col0 + row;
            gload16(Bseg + (size_t)gcol*ldbs + k0 + schk*8, &Bs[(w*2 + j) * 64]);
        }
        asm volatile("s_waitcnt vmcnt(0)" ::: "memory");
        __syncthreads();

        bf16x8 a[4][2], b[2][2];
        #pragma unroll
        for (int fm = 0; fm < 4; ++fm) {
            int row = wm*64 + fm*16 + (lane & 15);
            #pragma unroll
            for (int ks = 0; ks < 2; ++ks)
                a[fm][ks] = As[row*8 + ((ks*4 + (lane>>4)) ^ (row & 7))];
        }
        #pragma unroll
        for (int fn = 0; fn < 2; ++fn) {
            int col = wn*32 + fn*16 + (lane & 15);
            #pragma unroll
            for (int ks = 0; ks < 2; ++ks)
                b[fn][ks] = Bs[col*8 + ((ks*4 + (lane>>4)) ^ (col & 7))];
        }
        #pragma unroll
        for (int ks = 0; ks < 2; ++ks)
            #pragma unroll
            for (int fm = 0; fm < 4; ++fm)
                #pragma unroll
                for (int fn = 0; fn < 2; ++fn)
                    acc[fm][fn] = __builtin_amdgcn_mfma_f32_16x16x32_bf16(
                        a[fm][ks], b[fn][ks], acc[fm][fn], 0, 0, 0);
        __syncthreads();
    }

    float* Cf = (zz == 0) ? Cf0 : (zz == 1) ? Cf1 : (zz == 2) ? Cf2 : Cf3;
    #pragma unroll
    for (int fm = 0; fm < 4; ++fm) {
        #pragma unroll
        for (int fn = 0; fn < 2; ++fn) {
            int gc = col0 + wn*32 + fn*16 + (lane & 15);
            float bs = (zz == 0) ? bias[gc] : 0.f;
            #pragma unroll
            for (int r = 0; r < 4; ++r) {
                int gr = row0 + wm*64 + fm*16 + (lane>>4)*4 + r;
                Cf[(size_t)gr*512 + gc] = acc[fm][fn][r] + bs;
            }
        }
    }
}

// =====================================================================================
// Small-M (M=16) MFMA GEMM, one wave = 16x16xK tile, no LDS.
__global__ __launch_bounds__(256) void hgemm16_kernel(
    const bh16* __restrict__ A, int lda, long aZ,
    const bh16* __restrict__ Bt, int ldb,
    const float* __restrict__ bias,
    const float* __restrict__ pre,
    float* __restrict__ Of, bh16* __restrict__ Ob, long oZ,
    int N, int K, int act,
    float* __restrict__ curf, bh16* __restrict__ curb,
    const float* __restrict__ scaleptr)
{
    const int z = blockIdx.z;
    A += (long)z * aZ;
    const int lane = threadIdx.x & 63, w = threadIdx.x >> 6;
    const int col0 = blockIdx.x * 64 + w * 16;
    const int ar = lane & 15;
    const int koff = (lane >> 4) * 8;
    const bh16* arow = A + (size_t)ar * lda + koff;
    const bh16* brow = Bt + (size_t)(col0 + ar) * ldb + koff;
    f32x4 acc = {0.f, 0.f, 0.f, 0.f};
    const int nkt = K >> 5;
    for (int kt0 = 0; kt0 < nkt; kt0 += 8) {
        bf16x8 av[8], bv[8];
        #pragma unroll
        for (int j = 0; j < 8; ++j) {
            av[j] = *(const bf16x8*)(arow + (size_t)(kt0 + j) * 32);
            bv[j] = *(const bf16x8*)(brow + (size_t)(kt0 + j) * 32);
        }
        #pragma unroll
        for (int j = 0; j < 8; ++j)
            acc = __builtin_amdgcn_mfma_f32_16x16x32_bf16(av[j], bv[j], acc, 0, 0, 0);
    }
    const int col = col0 + ar;
    float bs = bias ? bias[col] : 0.f;
    float sc = scaleptr ? *scaleptr : 0.f;
    #pragma unroll
    for (int r = 0; r < 4; ++r) {
        int row = (lane >> 4) * 4 + r;
        float v = acc[r] + bs;
        if (pre) v += pre[(size_t)row * N + col];
        if (act == ACT_SILU)      v = v / (1.f + expf(-v));
        else if (act == ACT_TANH) v = tanhf(v);
        if (curf) {
            size_t o = (size_t)row * 512 + col;
            float nc = curf[o] - v * sc;
            curf[o] = nc;
            curb[o] = __float2bfloat16(nc);
        } else {
            size_t o = (size_t)z * oZ + (size_t)row * N + col;
            if (Of) Of[o] = v;
            if (Ob) Ob[o] = __float2bfloat16(v);
        }
    }
}

// ---------------- head3 helpers ----------------
__device__ __forceinline__ void bload512(const bh16* Bt, int ldb, int col0, int lane, bf16x8 bv[16])
{
    const int ar = lane & 15;
    const int koff = (lane >> 4) * 8;
    const bh16* brow = Bt + (size_t)(col0 + ar) * ldb + koff;
    #pragma unroll
    for (int j = 0; j < 16; ++j)
        bv[j] = *(const bf16x8*)(brow + (size_t)j * 32);
}

__device__ __forceinline__ f32x4 lmfma512(const unsigned short* A, int lda, int lane, const bf16x8 bv[16])
{
    const int ar = lane & 15;
    const int koff = (lane >> 4) * 8;
    const unsigned short* arow = A + (size_t)ar * lda + koff;
    f32x4 acc = {0.f, 0.f, 0.f, 0.f};
    #pragma unroll
    for (int j = 0; j < 16; ++j) {
        bf16x8 av = *(const bf16x8*)(arow + (size_t)j * 32);
        acc = __builtin_amdgcn_mfma_f32_16x16x32_bf16(av, bv[j], acc, 0, 0, 0);
    }
    return acc;
}

__device__ __forceinline__ f32x4 lslice(const unsigned short* A, int lda, const bh16* Bt, int ldb,
                                        int col0, int K, int lane)
{
    const int ar = lane & 15;
    const int koff = (lane >> 4) * 8;
    const unsigned short* arow = A + (size_t)ar * lda + koff;
    const bh16* brow = Bt + (size_t)(col0 + ar) * ldb + koff;
    f32x4 acc = {0.f, 0.f, 0.f, 0.f};
    const int nkt = K >> 5;
    for (int kt0 = 0; kt0 < nkt; kt0 += 8) {
        bf16x8 av[8], bv[8];
        #pragma unroll
        for (int j = 0; j < 8; ++j) {
            av[j] = *(const bf16x8*)(arow + (size_t)(kt0 + j) * 32);
            bv[j] = *(const bf16x8*)(brow + (size_t)(kt0 + j) * 32);
        }
        #pragma unroll
        for (int j = 0; j < 8; ++j)
            acc = __builtin_amdgcn_mfma_f32_16x16x32_bf16(av[j], bv[j], acc, 0, 0, 0);
    }
    return acc;
}

__device__ __forceinline__ void st_store(unsigned* st, int row, int colr, int lane, float v)
{
    float other = __shfl_xor(v, 1);
    if (!(lane & 1)) {
        unsigned lo = (unsigned)__bfloat16_as_ushort(__float2bfloat16(v));
        unsigned hi = (unsigned)__bfloat16_as_ushort(__float2bfloat16(other));
        __hip_atomic_store(st + ((row * 512 + colr) >> 1), lo | (hi << 16),
                           __ATOMIC_RELAXED, __HIP_MEMORY_SCOPE_AGENT);
    }
}

__device__ __forceinline__ void st_stage(unsigned short* ALds, const unsigned* st, int tid)
{
    const unsigned long long* st64 = (const unsigned long long*)st;
    for (int e = tid; e < 2048; e += 256) {
        unsigned long long uv = __hip_atomic_load(st64 + e, __ATOMIC_RELAXED, __HIP_MEMORY_SCOPE_AGENT);
        int row = e >> 7, cp = (e & 127) << 2;
        *(unsigned long long*)(ALds + row * 520 + cp) = uv;
    }
    __syncthreads();
}

__device__ __forceinline__ void gridbar(int* ctr, int* bar)
{
    __syncthreads();
    if (threadIdx.x == 0) {
        *bar += 8;
        __hip_atomic_fetch_add(ctr, 1, __ATOMIC_RELAXED, __HIP_MEMORY_SCOPE_AGENT);
        while (__hip_atomic_load(ctr, __ATOMIC_RELAXED, __HIP_MEMORY_SCOPE_AGENT) < *bar)
            __builtin_amdgcn_s_sleep(1);
    }
    __syncthreads();
}

// =====================================================================================
// Persistent head v3: weight prefetch hides load latency under barrier; u64 staging.
__global__ __launch_bounds__(256) void head3_kernel(
    const float* __restrict__ h,
    const bh16* __restrict__ mm1T, const float* __restrict__ mm1b,
    const bh16* __restrict__ mm2T, const float* __restrict__ mm2b,
    const bh16* __restrict__ dn1T,
    const bh16* __restrict__ dn2T, const float* __restrict__ dn2b,
    const bh16* __restrict__ dn3T, const float* __restrict__ dn3b,
    const bh16* __restrict__ outT, const float* __restrict__ outb,
    const float* __restrict__ pre1, const float* __restrict__ nsched,
    unsigned* __restrict__ stTM, unsigned* __restrict__ stCur,
    unsigned* __restrict__ stD1, unsigned* __restrict__ stD2,
    float* __restrict__ out, int* __restrict__ ctr)
{
    __shared__ __align__(16) unsigned short catL[16 * 1032];
    __shared__ __align__(16) unsigned short ALds[16 * 520];
    const int bx = blockIdx.x;
    const int tid = threadIdx.x;
    const int lane = tid & 63, w = tid >> 6;
    int bar = 0;
    const int col0 = bx * 64 + w * 16;
    const int colr = col0 + (lane & 15);
    const int row0 = (lane >> 4) * 4;
    bf16x8 bv[16];

    for (int e = tid; e < 16 * 1024; e += 256) {
        int k = e & 1023, b = e >> 10;
        float v = (k < 512) ? h[((size_t)b * TT + 255) * DD + k]
                            : h[((size_t)b * TT + 254) * DD + (k - 512)];
        catL[b * 1032 + k] = __bfloat16_as_ushort(__float2bfloat16(v));
    }
    __syncthreads();

    {
        f32x4 acc = lslice(catL, 1032, mm1T, 1024, col0, 1024, lane);
        float bs = mm1b[colr];
        #pragma unroll
        for (int r = 0; r < 4; ++r)
            st_store(stTM, row0 + r, colr, lane, tanhf(acc[r] + bs));
    }
    bload512(mm2T, 512, col0, lane, bv);
    gridbar(ctr, &bar);

    float cur_reg[4];
    {
        st_stage(ALds, stTM, tid);
        f32x4 acc = lmfma512(ALds, 520, lane, bv);
        float bs = mm2b[colr];
        #pragma unroll
        for (int r = 0; r < 4; ++r) {
            float cv = h[((size_t)(row0 + r) * TT + 255) * DD + colr] + acc[r] + bs;
            cur_reg[r] = cv;
            st_store(stCur, row0 + r, colr, lane, cv);
        }
    }
    bload512(dn1T, 1024, col0, lane, bv);
    gridbar(ctr, &bar);

    for (int t = 0; t < SS; ++t) {
        float sc = nsched[t];
        {
            st_stage(ALds, stCur, tid);
            f32x4 acc = lmfma512(ALds, 520, lane, bv);
            #pragma unroll
            for (int r = 0; r < 4; ++r) {
                float v = acc[r] + pre1[(size_t)t * 8192 + (row0 + r) * 512 + colr];
                v = v / (1.f + expf(-v));
                st_store(stD1, row0 + r, colr, lane, v);
            }
        }
        bload512(dn2T, 512, col0, lane, bv);
        gridbar(ctr, &bar);
        {
            st_stage(ALds, stD1, tid);
            f32x4 acc = lmfma512(ALds, 520, lane, bv);
            float bs = dn2b[colr];
            #pragma unroll
            for (int r = 0; r < 4; ++r) {
                float v = acc[r] + bs;
                v = v / (1.f + expf(-v));
                st_store(stD2, row0 + r, colr, lane, v);
            }
        }
        bload512(dn3T, 512, col0, lane, bv);
        gridbar(ctr, &bar);
        {
            st_stage(ALds, stD2, tid);
            f32x4 acc = lmfma512(ALds, 520, lane, bv);
            float bs = dn3b[colr];
            #pragma unroll
            for (int r = 0; r < 4; ++r) {
                float nc = cur_reg[r] - (acc[r] + bs) * sc;
                cur_reg[r] = nc;
                st_store(stCur, row0 + r, colr, lane, nc);
            }
        }
        if (t < SS - 1) bload512(dn1T, 1024, col0, lane, bv);
        else if (bx < 6) bload512(outT, 512, col0, lane, bv);
        gridbar(ctr, &bar);
    }

    {
        st_stage(ALds, stCur, tid);
        if (bx < 6) {
            f32x4 acc = lmfma512(ALds, 520, lane, bv);
            float bs = outb[colr];
            #pragma unroll
            for (int r = 0; r < 4; ++r)
                out[(size_t)(row0 + r) * 384 + colr] = acc[r] + bs;
        }
    }
}

// ---------------- wavelet: in-kernel filter softmax + dec (LDS tile) + interp ----------------
__global__ __launch_bounds__(256) void wave4_kernel(const bh16* __restrict__ hb,
                                                    const float* __restrict__ wav0,
                                                    const float* __restrict__ wav1,
                                                    const float* __restrict__ wav2,
                                                    const float* __restrict__ wav3,
                                                    int l,
                                                    bh16* __restrict__ comb)
{
    __shared__ float dtile[66 * 64];
    __shared__ float ftile[32 * 64];
    const int dblk = blockIdx.x;
    const int iy = blockIdx.y;
    const int b = blockIdx.z;
    const int i = iy >> 1, thalf = iy & 1;
    const int Karr[4] = {4, 8, 16, 32};
    const int K = Karr[i], sv = 2 << i, Ti = 128 >> i;
    const int tid = threadIdx.x;
    const int dbase = dblk * 64;
    if (tid < 64) {
        const float* wsrc = (i == 0) ? wav0 : (i == 1) ? wav1 : (i == 2) ? wav2 : wav3;
        const float* row = wsrc + ((size_t)l * DD + dbase + tid) * K;
        float mx = -1e30f;
        for (int k = 0; k < K; ++k) mx = fmaxf(mx, row[k]);
        float s = 0.f;
        for (int k = 0; k < K; ++k) { float e = expf(row[k] - mx); ftile[k*64 + tid] = e; s += e; }
        float inv = 1.f / s;
        for (int k = 0; k < K; ++k) ftile[k*64 + tid] *= inv;
    }
    const float invsv = 1.f / (float)sv;
    const int t0 = thalf * 128;
    float p0 = ((float)t0 + 0.5f) * invsv - 0.5f;
    p0 = fminf(fmaxf(p0, 0.f), (float)(Ti - 1));
    const int jbase = (int)p0;
    float p1 = ((float)(t0 + 127) + 0.5f) * invsv - 0.5f;
    p1 = fminf(fmaxf(p1, 0.f), (float)(Ti - 1));
    const int him = min((int)p1 + 1, Ti - 1);
    const int jcount = him - jbase + 1;     // <= 66
    __syncthreads();
    const bh16* hcol = hb + (size_t)b * (TT * DD) + dbase;
    for (int e = tid; e < jcount * 64; e += 256) {
        int jl = e >> 6, d0 = e & 63;
        int j = jbase + jl;
        int tb = j * sv - (K - 1);
        float acc = 0.f;
        #pragma unroll 4
        for (int k = 0; k < K; ++k) {
            int t = tb + k;
            if (t >= 0)
                acc += b2f(*(const unsigned short*)(hcol + (size_t)t * DD + d0)) * ftile[k * 64 + d0];
        }
        dtile[jl * 64 + d0] = acc;
    }
    __syncthreads();
    for (int e = tid; e < 128 * 64; e += 256) {
        int tl = e >> 6, d0 = e & 63;
        int t = t0 + tl;
        float pos = ((float)t + 0.5f) * invsv - 0.5f;
        pos = fminf(fmaxf(pos, 0.f), (float)(Ti - 1));
        int lo = (int)pos;
        int hi = min(lo + 1, Ti - 1);
        float w = pos - (float)lo;
        float v = dtile[(lo - jbase) * 64 + d0] * (1.f - w) + dtile[(hi - jbase) * 64 + d0] * w;
        comb[((size_t)b * TT + t) * 2048 + i * 512 + dbase + d0] = __float2bfloat16(v);
    }
}

// ---------------- h = layernorm(s0+s1+s2+s3 + h)*g + b, dual fp32+bf16 out ----------------
__global__ __launch_bounds__(256) void add_ln_kernel(const float* __restrict__ s0, const float* __restrict__ s1,
                                                     const float* __restrict__ s2, const float* __restrict__ s3,
                                                     float* __restrict__ h, bh16* __restrict__ hb,
                                                     const float* __restrict__ g, const float* __restrict__ be)
{
    int lane = threadIdx.x & 63, wid = threadIdx.x >> 6;
    size_t row = (size_t)blockIdx.x * 4 + wid;
    const float* sr0 = s0 + row * DD;
    const float* sr1 = s1 + row * DD;
    const float* sr2 = s2 + row * DD;
    const float* sr3 = s3 + row * DD;
    float* hr = h + row * DD;
    bh16* hbr = hb + row * DD;
    float xv[8]; float sum = 0.f;
    #pragma unroll
    for (int u = 0; u < 8; ++u) {
        int c = lane + u * 64;
        xv[u] = sr0[c] + sr1[c] + sr2[c] + sr3[c] + hr[c];
        sum += xv[u];
    }
    #pragma unroll
    for (int off = 32; off; off >>= 1) sum += __shfl_xor(sum, off);
    float mu = sum * (1.f / 512.f);
    float sq = 0.f;
    #pragma unroll
    for (int u = 0; u < 8; ++u) { float d = xv[u] - mu; sq += d * d; }
    #pragma unroll
    for (int off = 32; off; off >>= 1) sq += __shfl_xor(sq, off);
    float rstd = 1.f / sqrtf(sq * (1.f / 512.f) + 1e-5f);
    #pragma unroll
    for (int u = 0; u < 8; ++u) {
        int c = lane + u * 64;
        float v = (xv[u] - mu) * rstd * g[c] + be[c];
        hr[c] = v;
        hbr[c] = __float2bfloat16(v);
    }
}

// ---------------- weight transpose-convert ----------------
__global__ __launch_bounds__(256) void wtrans_kernel(const float* __restrict__ W, bh16* __restrict__ Wt,
                                                     int K, int N, long lstride)
{
    int l = blockIdx.z;
    const float* Wl = W + (size_t)l * K * N;
    bh16* Wo = Wt + (size_t)l * lstride;
    __shared__ float tile[32][33];
    int n0 = blockIdx.x * 32, k0 = blockIdx.y * 32;
    int lx = threadIdx.x & 31, ly = threadIdx.x >> 5;
    #pragma unroll
    for (int j = 0; j < 4; ++j) {
        int kk = ly + j * 8;
        tile[kk][lx] = Wl[(size_t)(k0 + kk) * N + n0 + lx];
    }
    __syncthreads();
    #pragma unroll
    for (int j = 0; j < 4; ++j) {
        int nr = ly + j * 8;
        Wo[(size_t)(n0 + nr) * K + k0 + lx] = __float2bfloat16(tile[lx][nr]);
    }
}

// ---------------- fused qkv|te1 transpose: grid (50, 16, 6) ----------------
__global__ __launch_bounds__(256) void wtrans4_kernel(const float* __restrict__ gq, const float* __restrict__ gk,
                                                      const float* __restrict__ gv, const float* __restrict__ te1,
                                                      bh16* __restrict__ qkvT)
{
    int bxx = blockIdx.x, l = blockIdx.z;
    const float* W; long off; int N; int n0;
    if (bxx < 16)      { W = gq;  off = 0;      N = 512; n0 = bxx * 32; }
    else if (bxx < 32) { W = gk;  off = 262144; N = 512; n0 = (bxx - 16) * 32; }
    else if (bxx < 48) { W = gv;  off = 524288; N = 512; n0 = (bxx - 32) * 32; }
    else               { W = te1; off = 786432; N = 64;  n0 = (bxx - 48) * 32; }
    const float* Wl = W + (size_t)l * 512 * N;
    bh16* Wo = qkvT + (size_t)l * 819200 + off;
    __shared__ float tile[32][33];
    int k0 = blockIdx.y * 32;
    int lx = threadIdx.x & 31, ly = threadIdx.x >> 5;
    #pragma unroll
    for (int j = 0; j < 4; ++j) {
        int kk = ly + j * 8;
        tile[kk][lx] = Wl[(size_t)(k0 + kk) * N + n0 + lx];
    }
    __syncthreads();
    #pragma unroll
    for (int j = 0; j < 4; ++j) {
        int nr = ly + j * 8;
        Wo[(size_t)(n0 + nr) * 512 + k0 + lx] = __float2bfloat16(tile[lx][nr]);
    }
}

// ---------------- fused head weight transpose: 1984 blocks ----------------
__global__ __launch_bounds__(256) void wtransH_kernel(
    const float* __restrict__ mm1w, const float* __restrict__ mm2w,
    const float* __restrict__ dn1w, const float* __restrict__ dn2w,
    const float* __restrict__ dn3w, const float* __restrict__ outw,
    bh16* __restrict__ mm1T, bh16* __restrict__ mm2T, bh16* __restrict__ dn1T,
    bh16* __restrict__ dn2T, bh16* __restrict__ dn3T, bh16* __restrict__ outT)
{
    int bx = blockIdx.x;
    const float* W; bh16* Wo; int K, N, bloc;
    if (bx < 512)       { W = mm1w; Wo = mm1T; K = 1024; N = 512; bloc = bx; }
    else if (bx < 768)  { W = mm2w; Wo = mm2T; K = 512;  N = 512; bloc = bx - 512; }
    else if (bx < 1280) { W = dn1w; Wo = dn1T; K = 1024; N = 512; bloc = bx - 768; }
    else if (bx < 1536) { W = dn2w; Wo = dn2T; K = 512;  N = 512; bloc = bx - 1280; }
    else if (bx < 1792) { W = dn3w; Wo = dn3T; K = 512;  N = 512; bloc = bx - 1536; }
    else                { W = outw; Wo = outT; K = 512;  N = 384; bloc = bx - 1792; }
    int nblk = N / 32;
    int n0 = (bloc % nblk) * 32, k0 = (bloc / nblk) * 32;
    __shared__ float tile[32][33];
    int lx = threadIdx.x & 31, ly = threadIdx.x >> 5;
    #pragma unroll
    for (int j = 0; j < 4; ++j) {
        int kk = ly + j * 8;
        tile[kk][lx] = W[(size_t)(k0 + kk) * N + n0 + lx];
    }
    __syncthreads();
    #pragma unroll
    for (int j = 0; j < 4; ++j) {
        int nr = ly + j * 8;
        Wo[(size_t)(n0 + nr) * K + k0 + lx] = __float2bfloat16(tile[lx][nr]);
    }
}

// ---------------- cc_w [L][O][I][3] f32 -> ccT [L][O][tap*512+I] bf16 ----------------
__global__ __launch_bounds__(256) void ccconv_kernel(const float* __restrict__ ccw, bh16* __restrict__ ccT)
{
    size_t idx = (size_t)blockIdx.x * 256 + threadIdx.x;   // 6*512*1536
    int i = idx & 511; size_t rem = idx >> 9;
    int tap = (int)(rem % 3); rem /= 3;
    int o = (int)(rem & 511); int l = (int)(rem >> 9);
    ccT[idx] = __float2bfloat16(ccw[(((size_t)l*512 + o)*512 + i)*3 + tap]);
}

// ---------------- qkv|te1 bias concat [L][1600] + fused-epilogue bias sum [L][512] ----------------
__global__ __launch_bounds__(256) void qkvbias_kernel(const float* __restrict__ qb_, const float* __restrict__ kb_,
                                                      const float* __restrict__ vb_, const float* __restrict__ t1b_,
                                                      float* __restrict__ ob,
                                                      const float* __restrict__ gob, const float* __restrict__ wrb,
                                                      const float* __restrict__ tdb, const float* __restrict__ ccb,
                                                      float* __restrict__ bsum)
{
    int idx = blockIdx.x * 256 + threadIdx.x;
    if (idx < 6 * 1600) {
        int l = idx / 1600, n = idx % 1600;
        float v = (n < 512) ? qb_[l*512 + n]
                : (n < 1024) ? kb_[l*512 + n - 512]
                : (n < 1536) ? vb_[l*512 + n - 1024]
                : t1b_[l*64 + n - 1536];
        ob[idx] = v;
    }
    if (idx < 6 * 512) {
        bsum[idx] = gob[idx] + wrb[idx] + tdb[idx] + ccb[idx];
    }
}

// ---------------- x f32 -> bf16 ----------------
__global__ __launch_bounds__(256) void convx_kernel(const float* __restrict__ x, bh16* __restrict__ xb)
{
    size_t idx = (size_t)blockIdx.x * 256 + threadIdx.x;
    xb[idx] = __float2bfloat16(x[idx]);
}

// ---------------- E matrix: row (t,b) = [sched[t]*noise[t,b,:] | temb[t]] ----------------
__global__ __launch_bounds__(256) void build_E_kernel(const float* __restrict__ noise, const float* __restrict__ sched,
                                                      bh16* __restrict__ E)
{
    int idx = blockIdx.x * 256 + threadIdx.x;   // 10*16*1024
    if (idx >= SS * BB * 1024) return;
    int k = idx & 1023; int rem = idx >> 10; int b = rem & 15; int t = rem >> 4;
    float v;
    if (k < 512) {
        v = sched[t] * noise[((size_t)t * BB + b) * 512 + k];
    } else {
        int j = k - 512;
        const float kfac = -9.210340371976184f / 255.f;
        v = (j < 256) ? sinf((float)t * expf((float)j * kfac))
                      : cosf((float)t * expf((float)(j - 256) * kfac));
    }
    E[idx] = __float2bfloat16(v);
}

// ---------------- init: zero page, loss, grid-barrier counter ----------------
__global__ void init_kernel(bh16* zp, float* loss, int* ctr)
{
    int t = threadIdx.x;
    if (t < 64) zp[t] = __float2bfloat16(0.f);
    if (t == 64) *loss = 0.f;
    if (t == 65) *ctr = 0;
}

__global__ void fail_kernel(float* p) { p[0] = 1e30f; }

// =====================================================================================
extern "C" void kernel_launch(void* const* d_in, const int* in_sizes, int n_in,
                              void* d_out, int out_size, void* d_ws, size_t ws_size,
                              hipStream_t stream)
{
    const float* x      = (const float*)d_in[0];
    const float* in_w   = (const float*)d_in[1];
    const float* in_b   = (const float*)d_in[2];
    const float* gq_w   = (const float*)d_in[3];
    const float* gq_b   = (const float*)d_in[4];
    const float* gk_w   = (const float*)d_in[5];
    const float* gk_b   = (const float*)d_in[6];
    const float* gv_w   = (const float*)d_in[7];
    const float* gv_b   = (const float*)d_in[8];
    const float* go_w   = (const float*)d_in[9];
    const float* go_b   = (const float*)d_in[10];
    const float* curv   = (const float*)d_in[11];
    const float* wav0   = (const float*)d_in[12];
    const float* wav1   = (const float*)d_in[13];
    const float* wav2   = (const float*)d_in[14];
    const float* wav3   = (const float*)d_in[15];
    const float* wrec_w = (const float*)d_in[16];
    const float* wrec_b = (const float*)d_in[17];
    const float* te1_w  = (const float*)d_in[18];
    const float* te1_b  = (const float*)d_in[19];
    const float* te2_w  = (const float*)d_in[20];
    const float* te2_b  = (const float*)d_in[21];
    const float* td1_w  = (const float*)d_in[22];
    const float* td1_b  = (const float*)d_in[23];
    const float* td2_w  = (const float*)d_in[24];
    const float* td2_b  = (const float*)d_in[25];
    const float* bd_w   = (const float*)d_in[26];
    const float* bd_b   = (const float*)d_in[27];
    const float* cc_w   = (const float*)d_in[28];
    const float* cc_b   = (const float*)d_in[29];
    const float* ln_g   = (const float*)d_in[30];
    const float* ln_b   = (const float*)d_in[31];
    const float* mm1_w  = (const float*)d_in[32];
    const float* mm1_b  = (const float*)d_in[33];
    const float* mm2_w  = (const float*)d_in[34];
    const float* mm2_b  = (const float*)d_in[35];
    const float* dn1_w  = (const float*)d_in[36];
    const float* dn1_b  = (const float*)d_in[37];
    const float* dn2_w  = (const float*)d_in[38];
    const float* dn2_b  = (const float*)d_in[39];
    const float* dn3_w  = (const float*)d_in[40];
    const float* dn3_b  = (const float*)d_in[41];
    const float* out_w  = (const float*)d_in[42];
    const float* out_b  = (const float*)d_in[43];
    const float* nsched = (const float*)d_in[44];
    const float* noise  = (const float*)d_in[45];
    float* out = (float*)d_out;
    float* ws  = (float*)d_ws;

    // ---- fp32 workspace layout (float offsets) ----
    const size_t o_h   = 0;          // 2097152
    const size_t o_dec = 2097152;    // 2097152 (s2 partial; pre1 for head)
    const size_t o_s   = 4194304;    // 2097152
    const size_t o_at  = 6619136;    // 8388608: comb (bf16, first half) + s3/s4 partials
    const size_t o_qkb = 15054848;   // 9600
    const size_t o_bs  = 15064448;   // 3072
    const size_t o_ctr = 15067520;   // 1 (int)
    const size_t FP32_TOTAL = 15095808;
    // ---- bf16 region (element offsets from bp) ----
    const size_t b_xb   = 0;          // 1572864
    const size_t b_hb   = 1572864;    // 2097152
    const size_t b_qkv  = 3670016;    // 6553600: packed qkv|t1 [4096][1600]
    const size_t b_pb   = 12320768;   // 8388608 (head scratch region)
    const size_t b_gmb  = 20709376;   // 2097152
    const size_t b_tdb  = 22806528;   // 2097152
    const size_t b_zp   = 25165824;   // 512
    const size_t b_inwT = 25166336;   // 196608
    const size_t b_qkvT = 25362944;   // 4915200
    const size_t b_goT  = 30278144;   // 1572864
    const size_t b_wrT  = 31851008;   // 6291456
    const size_t b_td1T = 38142464;   // 196608
    const size_t b_td2T = 38339072;   // 1572864
    const size_t b_te2T = 39911936;   // 24576
    const size_t b_ccT  = 39936512;   // 4718592
    const size_t BF16_TOTAL = 44655104;
    const size_t TOTAL_BYTES = FP32_TOTAL * 4 + BF16_TOTAL * 2;
    if (ws_size < TOTAL_BYTES) { fail_kernel<<<1, 1, 0, stream>>>(out); return; }

    float* h_   = ws + o_h;
    float* s2_  = ws + o_dec;
    float* s_   = ws + o_s;
    float* at_  = ws + o_at;
    float* s3_  = at_ + 4194304;
    float* s4_  = at_ + 6291456;
    float* qkvbias = ws + o_qkb;
    float* bsum = ws + o_bs;
    int*   ctr  = (int*)(ws + o_ctr);
    bh16* bp   = (bh16*)(ws + FP32_TOTAL);
    bh16* xb   = bp + b_xb;
    bh16* hb   = bp + b_hb;
    bh16* qkvb = bp + b_qkv;
    bh16* pb   = bp + b_pb;
    bh16* gmb  = bp + b_gmb;
    bh16* tdb  = bp + b_tdb;
    bh16* zp   = bp + b_zp;
    bh16* inwT = bp + b_inwT;
    bh16* qkvT = bp + b_qkvT;
    bh16* goT  = bp + b_goT;
    bh16* wrT  = bp + b_wrT;
    bh16* td1T = bp + b_td1T;
    bh16* td2T = bp + b_td2T;
    bh16* te2T = bp + b_te2T;
    bh16* ccT  = bp + b_ccT;
    bh16* combb = (bh16*)at_;

    // head bf16 scratch: aliased into pb region (dead during layers)
    bh16* dn1T  = pb;             // 524288
    bh16* dn2T  = pb + 524288;    // 262144
    bh16* dn3T  = pb + 786432;    // 262144
    bh16* mm1T  = pb + 1048576;   // 524288
    bh16* mm2T  = pb + 1572864;   // 262144
    bh16* outT  = pb + 1835008;   // 196608
    bh16* E16   = pb + 2031616;   // 163840
    float* pre1 = s2_;            // 81920 f32, aliases s2 after layers
    // head state (u32-packed bf16, agent-scope atomics): in s4_ area
    unsigned* stTM  = (unsigned*)s4_;          // 4096 u32 each
    unsigned* stCur = stTM + 4096;
    unsigned* stD1  = stTM + 8192;
    unsigned* stD2  = stTM + 12288;

    auto mgp = [&](const bh16* A, int lda, const bh16* Bt, int ldb,
                   const float* bias, float* Cf, bh16* Cb, int ldc,
                   int M, int N, int K, int shift, int accum, int act) {
        dim3 g((N + 63) / 64, M / 128, 1);
        mgemm_kernel<<<g, 256, 0, stream>>>(A, lda, Bt, ldb, bias, Cf, Cb, ldc, N, K,
                                            shift, accum, act, zp);
    };

    // ---- setup ----
    init_kernel<<<1, 128, 0, stream>>>(zp, out + BB * DIN, ctr);
    convx_kernel<<<BT * DIN / 256, 256, 0, stream>>>(x, xb);
    wtrans_kernel<<<dim3(DD/32, DIN/32, 1), 256, 0, stream>>>(in_w, inwT, DIN, DD, (long)DIN*DD);
    wtrans4_kernel<<<dim3(50, 16, 6), 256, 0, stream>>>(gq_w, gk_w, gv_w, te1_w, qkvT);
    qkvbias_kernel<<<38, 256, 0, stream>>>(gq_b, gk_b, gv_b, te1_b, qkvbias,
                                           go_b, wrec_b, td2_b, cc_b, bsum);
    wtrans_kernel<<<dim3(16, 16, 6), 256, 0, stream>>>(go_w, goT, DD, DD, (long)DD*DD);
    wtrans_kernel<<<dim3(16, 64, 6), 256, 0, stream>>>(wrec_w, wrT, 2048, DD, 2048L*DD);
    wtrans_kernel<<<dim3(16, 2, 6), 256, 0, stream>>>(td1_w, td1T, PP, DD, (long)PP*DD);
    wtrans_kernel<<<dim3(16, 16, 6), 256, 0, stream>>>(td2_w, td2T, DD, DD, (long)DD*DD);
    wtrans_kernel<<<dim3(2, 2, 6), 256, 0, stream>>>(te2_w, te2T, PP, PP, (long)PP*PP);
    ccconv_kernel<<<18432, 256, 0, stream>>>(cc_w, ccT);

    // h = x @ in_w + in_b  (fp32 + bf16)
    mgp(xb, DIN, inwT, DIN, in_b, h_, hb, DD, BT, DD, DIN, 0, 0, ACT_NONE);

    for (int l = 0; l < LL; ++l) {
        mgp(hb, DD, qkvT + (size_t)l*819200, DD, qkvbias + (size_t)l*1600,
            nullptr, qkvb, 1600, BT, 1600, DD, 0, 0, ACT_RELU_TAIL);
        fattn_kernel<<<dim3(4, 128), 256, 0, stream>>>(qkvb, curv + (size_t)l*HH, gmb);
        wave4_kernel<<<dim3(8, 8, 16), 256, 0, stream>>>(hb, wav0, wav1, wav2, wav3, l, combb);
        topo_kernel<<<dim3(8, 32), 256, 0, stream>>>(
            qkvb + 1536, te2T + (size_t)l*4096, te2_b + (size_t)l*PP,
            td1T + (size_t)l*32768, td1_b + (size_t)l*DD,
            bd_w + (size_t)l*PP*2, bd_b + (size_t)l*2, out + BB*DIN, tdb);
        fgemm_kernel<<<dim3(8, 32, 4), 256, 0, stream>>>(
            gmb, combb, tdb, hb,
            goT + (size_t)l*262144, wrT + (size_t)l*1048576,
            td2T + (size_t)l*262144, ccT + (size_t)l*786432,
            bsum + (size_t)l*512, s_, s2_, s3_, s4_, 1 << l, zp);
        add_ln_kernel<<<BT/4, 256, 0, stream>>>(s_, s2_, s3_, s4_, h_, hb, ln_g, ln_b);
    }

    // ---- head ----
    wtransH_kernel<<<1984, 256, 0, stream>>>(mm1_w, mm2_w, dn1_w, dn2_w, dn3_w, out_w,
                                             mm1T, mm2T, dn1T, dn2T, dn3T, outT);
    build_E_kernel<<<640, 256, 0, stream>>>(noise, nsched, E16);
    hgemm16_kernel<<<dim3(8, 1, SS), 256, 0, stream>>>(
        E16, 1024, 16*1024, dn1T, 1024, dn1_b, nullptr, pre1, nullptr, 8192,
        512, 1024, ACT_NONE, nullptr, nullptr, nullptr);
    head3_kernel<<<8, 256, 0, stream>>>(
        h_, mm1T, mm1_b, mm2T, mm2_b, dn1T, dn2T, dn2_b, dn3T, dn3_b,
        outT, out_b, pre1, nsched, stTM, stCur, stD1, stD2, out, ctr);
}

// Round 19
// 941.089 us; speedup vs baseline: 1.0720x; 1.0096x over previous
//
#include <hip/hip_runtime.h>
#include <hip/hip_bf16.h>
#include <math.h>

#define BB 16
#define TT 256
#define DIN 384
#define DD 512
#define LL 6
#define HH 8
#define PP 64
#define SS 10
#define BT (BB*TT)   // 4096

enum { ACT_NONE=0, ACT_RELU=1, ACT_TANH=2, ACT_SILU=3, ACT_RELU_TAIL=4 };

typedef __attribute__((ext_vector_type(8))) short bf16x8;
typedef __attribute__((ext_vector_type(4))) float f32x4;
typedef __hip_bfloat16 bh16;

typedef const __attribute__((address_space(1))) void gvoid_t;
typedef __attribute__((address_space(3))) void lvoid_t;
__device__ __forceinline__ void gload16(const void* g, void* l) {
    __builtin_amdgcn_global_load_lds((gvoid_t*)g, (lvoid_t*)l, 16, 0, 0);
}

__device__ __forceinline__ float b2f(unsigned short u) {
    return __uint_as_float(((unsigned int)u) << 16);
}

// bijective chunked XCD swizzle (m204) within one z-plane.
__device__ __forceinline__ void xcd_swizzle_always(int& bx, int& by) {
    int gx = gridDim.x;
    int nwg = gx * gridDim.y;
    int lid = by * gx + bx;
    int q = nwg >> 3, r = nwg & 7;
    int xcd = lid & 7, idx = lid >> 3;
    int swz = (xcd < r) ? (xcd * (q + 1) + idx) : (r * (q + 1) + (xcd - r) * q + idx);
    bx = swz % gx;
    by = swz / gx;
}
__device__ __forceinline__ void xcd_swizzle(int& bx, int& by) {
    if (gridDim.z == 1) xcd_swizzle_always(bx, by);
}

// =====================================================================================
// Generic bf16 MFMA GEMM: C = act(A @ Bt^T + bias)  (Bt stored [N][K])
__global__ __launch_bounds__(256) void mgemm_kernel(
    const bh16* __restrict__ A, int lda,
    const bh16* __restrict__ Bt, int ldb,
    const float* __restrict__ bias,
    float* __restrict__ Cf, bh16* __restrict__ Cb, int ldc,
    int N, int K, int shift, int accum, int act,
    const bh16* __restrict__ zp)
{
    __shared__ bf16x8 As[128*8];
    __shared__ bf16x8 Bs[64*8];

    int bx = blockIdx.x, by = blockIdx.y;
    xcd_swizzle(bx, by);

    const int tid  = threadIdx.x;
    const int lane = tid & 63, w = tid >> 6;
    const int wm = w >> 1, wn = w & 1;
    const int row0 = by * 128, col0 = bx * 64;

    f32x4 acc[4][2];
    #pragma unroll
    for (int i = 0; i < 4; ++i)
        #pragma unroll
        for (int j = 0; j < 2; ++j) acc[i][j] = (f32x4){0.f,0.f,0.f,0.f};

    const int nkt = K >> 6;
    for (int kt = 0; kt < nkt; ++kt) {
        int k0 = kt << 6;
        #pragma unroll
        for (int j = 0; j < 4; ++j) {
            int c = ((w*4 + j) << 6) + lane;
            int row = c >> 3, chk = c & 7;
            int schk = chk ^ (row & 7);
            int grow = row0 + row;
            const bh16* src = ((grow & 255) >= shift)
                ? (A + (size_t)(grow - shift)*lda + k0 + schk*8) : zp;
            gload16(src, &As[(w*4 + j) * 64]);
        }
        #pragma unroll
        for (int j = 0; j < 2; ++j) {
            int c = ((w*2 + j) << 6) + lane;
            int row = c >> 3, chk = c & 7;
            int schk = chk ^ (row & 7);
            int gcol = col0 + row;
            const bh16* src = (gcol < N)
                ? (Bt + (size_t)gcol*ldb + k0 + schk*8) : zp;
            gload16(src, &Bs[(w*2 + j) * 64]);
        }
        asm volatile("s_waitcnt vmcnt(0)" ::: "memory");
        __syncthreads();

        bf16x8 a[4][2], b[2][2];
        #pragma unroll
        for (int fm = 0; fm < 4; ++fm) {
            int row = wm*64 + fm*16 + (lane & 15);
            #pragma unroll
            for (int ks = 0; ks < 2; ++ks)
                a[fm][ks] = As[row*8 + ((ks*4 + (lane>>4)) ^ (row & 7))];
        }
        #pragma unroll
        for (int fn = 0; fn < 2; ++fn) {
            int col = wn*32 + fn*16 + (lane & 15);
            #pragma unroll
            for (int ks = 0; ks < 2; ++ks)
                b[fn][ks] = Bs[col*8 + ((ks*4 + (lane>>4)) ^ (col & 7))];
        }
        #pragma unroll
        for (int ks = 0; ks < 2; ++ks)
            #pragma unroll
            for (int fm = 0; fm < 4; ++fm)
                #pragma unroll
                for (int fn = 0; fn < 2; ++fn)
                    acc[fm][fn] = __builtin_amdgcn_mfma_f32_16x16x32_bf16(
                        a[fm][ks], b[fn][ks], acc[fm][fn], 0, 0, 0);
        __syncthreads();
    }

    #pragma unroll
    for (int fm = 0; fm < 4; ++fm) {
        #pragma unroll
        for (int fn = 0; fn < 2; ++fn) {
            int gc = col0 + wn*32 + fn*16 + (lane & 15);
            float bs = bias ? bias[gc] : 0.f;
            #pragma unroll
            for (int r = 0; r < 4; ++r) {
                int gr = row0 + wm*64 + fm*16 + (lane>>4)*4 + r;
                float v = acc[fm][fn][r] + bs;
                if (act == ACT_RELU) v = fmaxf(v, 0.f);
                else if (act == ACT_RELU_TAIL && gc >= 1536) v = fmaxf(v, 0.f);
                size_t o = (size_t)gr*ldc + gc;
                if (Cf) { if (accum) Cf[o] += v; else Cf[o] = v; }
                if (Cb) Cb[o] = __float2bfloat16(v);
            }
        }
    }
}

// =====================================================================================
// Fused topo: tf = t1@te2 + b, bd loss (bx==0), tdb = relu(tf@td1 + b). grid (8, 32).
__global__ __launch_bounds__(256) void topo_kernel(
    const bh16* __restrict__ t1,     // qkvb+1536, lda 1600
    const bh16* __restrict__ te2T,   // [64][64]
    const float* __restrict__ te2b,
    const bh16* __restrict__ td1T,   // [512][64]
    const float* __restrict__ td1b,
    const float* __restrict__ bdw, const float* __restrict__ bdb,
    float* __restrict__ loss,
    bh16* __restrict__ tdb)          // [4096][512]
{
    __shared__ bf16x8 As[128*8];
    __shared__ bf16x8 Bs[64*8];
    __shared__ float redT[2][128];
    __shared__ float bsumS;

    const int bx = blockIdx.x, by = blockIdx.y;
    const int lane = threadIdx.x & 63, w = threadIdx.x >> 6;
    const int wm = w >> 1, wn = w & 1;
    const int row0 = by * 128;

    #pragma unroll
    for (int j = 0; j < 4; ++j) {
        int c = ((w*4 + j) << 6) + lane;
        int row = c >> 3, chk = c & 7, schk = chk ^ (row & 7);
        gload16(t1 + (size_t)(row0 + row)*1600 + schk*8, &As[(w*4+j)*64]);
    }
    #pragma unroll
    for (int j = 0; j < 2; ++j) {
        int c = ((w*2 + j) << 6) + lane;
        int row = c >> 3, chk = c & 7, schk = chk ^ (row & 7);
        gload16(te2T + (size_t)row*64 + schk*8, &Bs[(w*2+j)*64]);
    }
    asm volatile("s_waitcnt vmcnt(0)" ::: "memory");
    __syncthreads();

    f32x4 acc[4][2];
    #pragma unroll
    for (int i = 0; i < 4; ++i)
        #pragma unroll
        for (int j = 0; j < 2; ++j) acc[i][j] = (f32x4){0.f,0.f,0.f,0.f};
    {
        bf16x8 a[4][2], b[2][2];
        #pragma unroll
        for (int fm = 0; fm < 4; ++fm) {
            int row = wm*64 + fm*16 + (lane & 15);
            #pragma unroll
            for (int ks = 0; ks < 2; ++ks)
                a[fm][ks] = As[row*8 + ((ks*4 + (lane>>4)) ^ (row & 7))];
        }
        #pragma unroll
        for (int fn = 0; fn < 2; ++fn) {
            int col = wn*32 + fn*16 + (lane & 15);
            #pragma unroll
            for (int ks = 0; ks < 2; ++ks)
                b[fn][ks] = Bs[col*8 + ((ks*4 + (lane>>4)) ^ (col & 7))];
        }
        #pragma unroll
        for (int ks = 0; ks < 2; ++ks)
            #pragma unroll
            for (int fm = 0; fm < 4; ++fm)
                #pragma unroll
                for (int fn = 0; fn < 2; ++fn)
                    acc[fm][fn] = __builtin_amdgcn_mfma_f32_16x16x32_bf16(
                        a[fm][ks], b[fn][ks], acc[fm][fn], 0, 0, 0);
    }
    #pragma unroll
    for (int fn = 0; fn < 2; ++fn) {
        int gc = wn*32 + fn*16 + (lane & 15);
        float bs = te2b[gc];
        #pragma unroll
        for (int fm = 0; fm < 4; ++fm)
            #pragma unroll
            for (int r = 0; r < 4; ++r) acc[fm][fn][r] += bs;
    }

    if (bx == 0) {
        float bconst = (bdb[0] - bdb[1]) + 0.1f;
        float wv[2];
        #pragma unroll
        for (int fn = 0; fn < 2; ++fn) {
            int gc = wn*32 + fn*16 + (lane & 15);
            wv[fn] = bdw[gc*2] - bdw[gc*2 + 1];
        }
        float dp[4][4];
        #pragma unroll
        for (int fm = 0; fm < 4; ++fm)
            #pragma unroll
            for (int r = 0; r < 4; ++r) {
                dp[fm][r] = acc[fm][0][r]*wv[0] + acc[fm][1][r]*wv[1];
                #pragma unroll
                for (int off = 1; off < 16; off <<= 1)
                    dp[fm][r] += __shfl_xor(dp[fm][r], off);
            }
        if ((lane & 15) == 0)
            #pragma unroll
            for (int fm = 0; fm < 4; ++fm)
                #pragma unroll
                for (int r = 0; r < 4; ++r)
                    redT[wn][wm*64 + fm*16 + (lane>>4)*4 + r] = dp[fm][r];
        if (threadIdx.x == 0) bsumS = 0.f;
        __syncthreads();
        if (wn == 0 && (lane & 15) == 0) {
            float ls = 0.f;
            #pragma unroll
            for (int fm = 0; fm < 4; ++fm)
                #pragma unroll
                for (int r = 0; r < 4; ++r) {
                    int rowl = wm*64 + fm*16 + (lane>>4)*4 + r;
                    ls += fmaxf(dp[fm][r] + redT[1][rowl] + bconst, 0.f);
                }
            atomicAdd(&bsumS, ls);
        }
        __syncthreads();
        if (threadIdx.x == 0) atomicAdd(loss, bsumS * (1.f / 4096.f));
    }

    __syncthreads();
    #pragma unroll
    for (int fm = 0; fm < 4; ++fm)
        #pragma unroll
        for (int fn = 0; fn < 2; ++fn)
            #pragma unroll
            for (int r = 0; r < 4; ++r) {
                int rowl = wm*64 + fm*16 + (lane>>4)*4 + r;
                int gc = wn*32 + fn*16 + (lane & 15);
                ((bh16*)As)[(rowl*8 + ((gc >> 3) ^ (rowl & 7)))*8 + (gc & 7)] =
                    __float2bfloat16(acc[fm][fn][r]);
            }
    #pragma unroll
    for (int j = 0; j < 2; ++j) {
        int c = ((w*2 + j) << 6) + lane;
        int row = c >> 3, chk = c & 7, schk = chk ^ (row & 7);
        gload16(td1T + (size_t)(bx*64 + row)*64 + schk*8, &Bs[(w*2+j)*64]);
    }
    asm volatile("s_waitcnt vmcnt(0)" ::: "memory");
    __syncthreads();

    f32x4 acc2[4][2];
    #pragma unroll
    for (int i = 0; i < 4; ++i)
        #pragma unroll
        for (int j = 0; j < 2; ++j) acc2[i][j] = (f32x4){0.f,0.f,0.f,0.f};
    {
        bf16x8 a[4][2], b[2][2];
        #pragma unroll
        for (int fm = 0; fm < 4; ++fm) {
            int row = wm*64 + fm*16 + (lane & 15);
            #pragma unroll
            for (int ks = 0; ks < 2; ++ks)
                a[fm][ks] = As[row*8 + ((ks*4 + (lane>>4)) ^ (row & 7))];
        }
        #pragma unroll
        for (int fn = 0; fn < 2; ++fn) {
            int col = wn*32 + fn*16 + (lane & 15);
            #pragma unroll
            for (int ks = 0; ks < 2; ++ks)
                b[fn][ks] = Bs[col*8 + ((ks*4 + (lane>>4)) ^ (col & 7))];
        }
        #pragma unroll
        for (int ks = 0; ks < 2; ++ks)
            #pragma unroll
            for (int fm = 0; fm < 4; ++fm)
                #pragma unroll
                for (int fn = 0; fn < 2; ++fn)
                    acc2[fm][fn] = __builtin_amdgcn_mfma_f32_16x16x32_bf16(
                        a[fm][ks], b[fn][ks], acc2[fm][fn], 0, 0, 0);
    }
    #pragma unroll
    for (int fm = 0; fm < 4; ++fm)
        #pragma unroll
        for (int fn = 0; fn < 2; ++fn) {
            int gcol = bx*64 + wn*32 + fn*16 + (lane & 15);
            float bs = td1b[gcol];
            #pragma unroll
            for (int r = 0; r < 4; ++r) {
                int gr = row0 + wm*64 + fm*16 + (lane>>4)*4 + r;
                tdb[(size_t)gr*512 + gcol] = __float2bfloat16(fmaxf(acc2[fm][fn][r] + bs, 0.f));
            }
        }
}

// =====================================================================================
// Fused attention: norms + QK^T + hyperbolic softmax + V-transpose + PV, one kernel.
__global__ __launch_bounds__(256) void fattn_kernel(
    const bh16* __restrict__ qkv,      // [4096][1600]: q@0, k@+512, v@+1024
    const float* __restrict__ curv,
    bh16* __restrict__ gmb)            // [4096][512]
{
    __shared__ bf16x8 Qs[64*8];
    __shared__ bf16x8 Ks[256*8];
    __shared__ __align__(16) bh16 Ps[64*64];
    __shared__ bf16x8 Bv[64*8];
    __shared__ unsigned short Vst[64*72];
    __shared__ float redA[2][64];
    __shared__ float redB[2][64];
    __shared__ float qnS[64];
    __shared__ float knS[256];

    const int rh = blockIdx.x;
    const int bh = blockIdx.y;
    const int b = bh >> 3, hh = bh & 7;
    const int lane = threadIdx.x & 63, w = threadIdx.x >> 6;
    const int wm = w >> 1, wn = w & 1;

    const bh16* qbase = qkv + hh * 64;
    const bh16* kbase = qkv + 512 + hh * 64;
    #pragma unroll
    for (int j = 0; j < 2; ++j) {
        int c = ((w*2 + j) << 6) + lane;
        int row = c >> 3, chk = c & 7, schk = chk ^ (row & 7);
        gload16(qbase + (size_t)(b*256 + rh*64 + row)*1600 + schk*8, &Qs[(w*2+j)*64]);
    }
    #pragma unroll
    for (int j = 0; j < 8; ++j) {
        int c = ((w*8 + j) << 6) + lane;
        int row = c >> 3, chk = c & 7, schk = chk ^ (row & 7);
        gload16(kbase + (size_t)(b*256 + row)*1600 + schk*8, &Ks[(w*8+j)*64]);
    }
    asm volatile("s_waitcnt vmcnt(0)" ::: "memory");
    __syncthreads();

    {
        int t = threadIdx.x;
        float s = 0.f;
        #pragma unroll
        for (int jj = 0; jj < 8; ++jj) {
            bf16x8 v = Ks[t*8 + ((t + jj) & 7)];
            #pragma unroll
            for (int e = 0; e < 8; ++e) { float f = b2f((unsigned short)v[e]); s += f * f; }
        }
        knS[t] = s;
        if (t < 64) {
            float sq = 0.f;
            #pragma unroll
            for (int jj = 0; jj < 8; ++jj) {
                bf16x8 v = Qs[t*8 + ((t + jj) & 7)];
                #pragma unroll
                for (int e = 0; e < 8; ++e) { float f = b2f((unsigned short)v[e]); sq += f * f; }
            }
            qnS[t] = sq;
        }
    }
    __syncthreads();

    f32x4 acc[2][8];
    #pragma unroll
    for (int i = 0; i < 2; ++i)
        #pragma unroll
        for (int j = 0; j < 8; ++j) acc[i][j] = (f32x4){0.f,0.f,0.f,0.f};

    bf16x8 af[2][2];
    #pragma unroll
    for (int fm = 0; fm < 2; ++fm) {
        int row = wm*32 + fm*16 + (lane & 15);
        #pragma unroll
        for (int ks = 0; ks < 2; ++ks)
            af[fm][ks] = Qs[row*8 + ((ks*4 + (lane>>4)) ^ (row & 7))];
    }
    #pragma unroll
    for (int fn = 0; fn < 8; ++fn) {
        int col = wn*128 + fn*16 + (lane & 15);
        #pragma unroll
        for (int ks = 0; ks < 2; ++ks) {
            bf16x8 bf = Ks[col*8 + ((ks*4 + (lane>>4)) ^ (col & 7))];
            #pragma unroll
            for (int fm = 0; fm < 2; ++fm)
                acc[fm][fn] = __builtin_amdgcn_mfma_f32_16x16x32_bf16(
                    af[fm][ks], bf, acc[fm][fn], 0, 0, 0);
        }
    }

    const float c_ = fabsf(curv[hh]) + 1e-8f;
    const float isc = 1.f / sqrtf(c_);
    float qnv[2][4], knv[8];
    #pragma unroll
    for (int fm = 0; fm < 2; ++fm)
        #pragma unroll
        for (int r = 0; r < 4; ++r)
            qnv[fm][r] = qnS[wm*32 + fm*16 + (lane>>4)*4 + r];
    #pragma unroll
    for (int fn = 0; fn < 8; ++fn)
        knv[fn] = knS[wn*128 + fn*16 + (lane & 15)];

    float rmax[2][4];
    #pragma unroll
    for (int fm = 0; fm < 2; ++fm)
        #pragma unroll
        for (int r = 0; r < 4; ++r) rmax[fm][r] = -1e30f;
    #pragma unroll
    for (int fm = 0; fm < 2; ++fm)
        #pragma unroll
        for (int fn = 0; fn < 8; ++fn)
            #pragma unroll
            for (int r = 0; r < 4; ++r) {
                float s = acc[fm][fn][r];
                float d2 = fmaxf(qnv[fm][r] + knv[fn] - 2.f * s, 0.f);
                float denom = fmaxf((1.f - c_ * qnv[fm][r]) * (1.f - c_ * knv[fn]), 1e-5f);
                float arg = fmaxf(1.f + (2.f * c_ * d2) / denom, 1.00001f);
                float dist = logf(arg + sqrtf((arg - 1.f) * (arg + 1.f))) * isc;
                float lg = -dist;
                acc[fm][fn][r] = lg;
                rmax[fm][r] = fmaxf(rmax[fm][r], lg);
            }
    #pragma unroll
    for (int off = 1; off < 16; off <<= 1)
        #pragma unroll
        for (int fm = 0; fm < 2; ++fm)
            #pragma unroll
            for (int r = 0; r < 4; ++r)
                rmax[fm][r] = fmaxf(rmax[fm][r], __shfl_xor(rmax[fm][r], off));
    if ((lane & 15) == 0)
        #pragma unroll
        for (int fm = 0; fm < 2; ++fm)
            #pragma unroll
            for (int r = 0; r < 4; ++r)
                redA[wn][wm*32 + fm*16 + (lane>>4)*4 + r] = rmax[fm][r];
    __syncthreads();
    #pragma unroll
    for (int fm = 0; fm < 2; ++fm)
        #pragma unroll
        for (int r = 0; r < 4; ++r)
            rmax[fm][r] = fmaxf(rmax[fm][r], redA[wn ^ 1][wm*32 + fm*16 + (lane>>4)*4 + r]);
    float rsum[2][4];
    #pragma unroll
    for (int fm = 0; fm < 2; ++fm)
        #pragma unroll
        for (int r = 0; r < 4; ++r) rsum[fm][r] = 0.f;
    #pragma unroll
    for (int fm = 0; fm < 2; ++fm)
        #pragma unroll
        for (int fn = 0; fn < 8; ++fn)
            #pragma unroll
            for (int r = 0; r < 4; ++r) {
                float e = expf(acc[fm][fn][r] - rmax[fm][r]);
                acc[fm][fn][r] = e;
                rsum[fm][r] += e;
            }
    #pragma unroll
    for (int off = 1; off < 16; off <<= 1)
        #pragma unroll
        for (int fm = 0; fm < 2; ++fm)
            #pragma unroll
            for (int r = 0; r < 4; ++r)
                rsum[fm][r] += __shfl_xor(rsum[fm][r], off);
    if ((lane & 15) == 0)
        #pragma unroll
        for (int fm = 0; fm < 2; ++fm)
            #pragma unroll
            for (int r = 0; r < 4; ++r)
                redB[wn][wm*32 + fm*16 + (lane>>4)*4 + r] = rsum[fm][r];
    __syncthreads();
    float pinv[2][4];
    #pragma unroll
    for (int fm = 0; fm < 2; ++fm)
        #pragma unroll
        for (int r = 0; r < 4; ++r)
            pinv[fm][r] = 1.f / (rsum[fm][r] + redB[wn ^ 1][wm*32 + fm*16 + (lane>>4)*4 + r]);

    f32x4 acc2[2][2];
    #pragma unroll
    for (int i = 0; i < 2; ++i)
        #pragma unroll
        for (int j = 0; j < 2; ++j) acc2[i][j] = (f32x4){0.f,0.f,0.f,0.f};

    const bh16* vbase = qkv + 1024 + hh * 64;
    for (int kt = 0; kt < 4; ++kt) {
        __syncthreads();
        if (wn == (kt >> 1)) {
            int fnb = (kt & 1) * 4;
            #pragma unroll
            for (int fm = 0; fm < 2; ++fm)
                #pragma unroll
                for (int fnl = 0; fnl < 4; ++fnl)
                    #pragma unroll
                    for (int r = 0; r < 4; ++r) {
                        int rowl = wm*32 + fm*16 + (lane>>4)*4 + r;
                        int kl = fnl*16 + (lane & 15);
                        float p = acc[fm][fnb + fnl][r] * pinv[fm][r];
                        Ps[(rowl*8 + ((kl >> 3) ^ (rowl & 7)))*8 + (kl & 7)] = __float2bfloat16(p);
                    }
        }
        #pragma unroll
        for (int j = 0; j < 2; ++j) {
            int c = threadIdx.x + j*256;
            int tr = c >> 3, chk = c & 7;
            bf16x8 v = *(const bf16x8*)(vbase + (size_t)(b*256 + kt*64 + tr)*1600 + chk*8);
            *(bf16x8*)(&Vst[tr*72 + chk*8]) = v;
        }
        __syncthreads();
        #pragma unroll
        for (int j = 0; j < 2; ++j) {
            int c = threadIdx.x + j*256;
            int col = c & 63, chk = c >> 6;
            bf16x8 v;
            #pragma unroll
            for (int e = 0; e < 8; ++e)
                v[e] = (short)Vst[(chk*8 + e)*72 + col];
            Bv[col*8 + (chk ^ (col & 7))] = v;
        }
        __syncthreads();

        bf16x8 pa[2][2], vb[2][2];
        #pragma unroll
        for (int fm = 0; fm < 2; ++fm) {
            int row = wm*32 + fm*16 + (lane & 15);
            #pragma unroll
            for (int ks = 0; ks < 2; ++ks)
                pa[fm][ks] = ((bf16x8*)Ps)[row*8 + ((ks*4 + (lane>>4)) ^ (row & 7))];
        }
        #pragma unroll
        for (int fn = 0; fn < 2; ++fn) {
            int col = wn*32 + fn*16 + (lane & 15);
            #pragma unroll
            for (int ks = 0; ks < 2; ++ks)
                vb[fn][ks] = Bv[col*8 + ((ks*4 + (lane>>4)) ^ (col & 7))];
        }
        #pragma unroll
        for (int ks = 0; ks < 2; ++ks)
            #pragma unroll
            for (int fm = 0; fm < 2; ++fm)
                #pragma unroll
                for (int fn = 0; fn < 2; ++fn)
                    acc2[fm][fn] = __builtin_amdgcn_mfma_f32_16x16x32_bf16(
                        pa[fm][ks], vb[fn][ks], acc2[fm][fn], 0, 0, 0);
    }

    #pragma unroll
    for (int fm = 0; fm < 2; ++fm)
        #pragma unroll
        for (int fn = 0; fn < 2; ++fn)
            #pragma unroll
            for (int r = 0; r < 4; ++r) {
                int rowl = wm*32 + fm*16 + (lane>>4)*4 + r;
                int col = wn*32 + fn*16 + (lane & 15);
                gmb[((size_t)(b*256 + rh*64 + rowl))*512 + hh*64 + col] =
                    __float2bfloat16(acc2[fm][fn][r]);
            }
}

// =====================================================================================
// Fused 4-segment GEMM, split-K=4 over blockIdx.z (18 kt each)
__global__ __launch_bounds__(256) void fgemm_kernel(
    const bh16* __restrict__ A0, const bh16* __restrict__ A1,
    const bh16* __restrict__ A2, const bh16* __restrict__ A3,
    const bh16* __restrict__ B0, const bh16* __restrict__ B1,
    const bh16* __restrict__ B2, const bh16* __restrict__ B3,
    const float* __restrict__ bias,
    float* __restrict__ Cf0, float* __restrict__ Cf1,
    float* __restrict__ Cf2, float* __restrict__ Cf3,
    int dil, const bh16* __restrict__ zp)
{
    __shared__ bf16x8 As[128*8];
    __shared__ bf16x8 Bs[64*8];

    int bx = blockIdx.x, by = blockIdx.y;
    xcd_swizzle_always(bx, by);
    const int zz = blockIdx.z;
    const int ktlo = zz * 18;
    const int kthi = ktlo + 18;

    const int tid  = threadIdx.x;
    const int lane = tid & 63, w = tid >> 6;
    const int wm = w >> 1, wn = w & 1;
    const int row0 = by * 128, col0 = bx * 64;

    f32x4 acc[4][2];
    #pragma unroll
    for (int i = 0; i < 4; ++i)
        #pragma unroll
        for (int j = 0; j < 2; ++j) acc[i][j] = (f32x4){0.f,0.f,0.f,0.f};

    for (int kt = ktlo; kt < kthi; ++kt) {
        const bh16* Aseg; const bh16* Bseg;
        int ldas, ldbs, k0, mask_sh, addr_sh;
        if (kt < 8) {
            Aseg = A0; Bseg = B0; ldas = 512; ldbs = 512;
            k0 = kt << 6; mask_sh = 0; addr_sh = 0;
        } else if (kt < 40) {
            Aseg = A1; Bseg = B1; ldas = 2048; ldbs = 2048;
            k0 = (kt - 8) << 6; mask_sh = 0; addr_sh = 0;
        } else if (kt < 48) {
            Aseg = A2; Bseg = B2; ldas = 512; ldbs = 512;
            k0 = (kt - 40) << 6; mask_sh = 0; addr_sh = 0;
        } else {
            int kl = kt - 48, tap = kl >> 3;
            Aseg = A3; Bseg = B3; ldas = 512; ldbs = 1536;
            k0 = kl << 6;
            mask_sh = (2 - tap) * dil;
            addr_sh = mask_sh + tap;
        }
        #pragma unroll
        for (int j = 0; j < 4; ++j) {
            int c = ((w*4 + j) << 6) + lane;
            int row = c >> 3, chk = c & 7;
            int schk = chk ^ (row & 7);
            int grow = row0 + row;
            const bh16* src = ((grow & 255) >= mask_sh)
                ? (Aseg + (size_t)(grow - addr_sh)*ldas + k0 + schk*8) : zp;
            gload16(src, &As[(w*4 + j) * 64]);
        }
        #pragma unroll
        for (int j = 0; j < 2; ++j) {
            int c = ((w*2 + j) << 6) + lane;
            int row = c >> 3, chk = c & 7;
            int schk = chk ^ (row & 7);
            int gcol = col0 + row;
            gload16(Bseg + (size_t)gcol*ldbs + k0 + schk*8, &Bs[(w*2 + j) * 64]);
        }
        asm volatile("s_waitcnt vmcnt(0)" ::: "memory");
        __syncthreads();

        bf16x8 a[4][2], b[2][2];
        #pragma unroll
        for (int fm = 0; fm < 4; ++fm) {
            int row = wm*64 + fm*16 + (lane & 15);
            #pragma unroll
            for (int ks = 0; ks < 2; ++ks)
                a[fm][ks] = As[row*8 + ((ks*4 + (lane>>4)) ^ (row & 7))];
        }
        #pragma unroll
        for (int fn = 0; fn < 2; ++fn) {
            int col = wn*32 + fn*16 + (lane & 15);
            #pragma unroll
            for (int ks = 0; ks < 2; ++ks)
                b[fn][ks] = Bs[col*8 + ((ks*4 + (lane>>4)) ^ (col & 7))];
        }
        #pragma unroll
        for (int ks = 0; ks < 2; ++ks)
            #pragma unroll
            for (int fm = 0; fm < 4; ++fm)
                #pragma unroll
                for (int fn = 0; fn < 2; ++fn)
                    acc[fm][fn] = __builtin_amdgcn_mfma_f32_16x16x32_bf16(
                        a[fm][ks], b[fn][ks], acc[fm][fn], 0, 0, 0);
        __syncthreads();
    }

    float* Cf = (zz == 0) ? Cf0 : (zz == 1) ? Cf1 : (zz == 2) ? Cf2 : Cf3;
    #pragma unroll
    for (int fm = 0; fm < 4; ++fm) {
        #pragma unroll
        for (int fn = 0; fn < 2; ++fn) {
            int gc = col0 + wn*32 + fn*16 + (lane & 15);
            float bs = (zz == 0) ? bias[gc] : 0.f;
            #pragma unroll
            for (int r = 0; r < 4; ++r) {
                int gr = row0 + wm*64 + fm*16 + (lane>>4)*4 + r;
                Cf[(size_t)gr*512 + gc] = acc[fm][fn][r] + bs;
            }
        }
    }
}

// =====================================================================================
// Small-M (M=16) MFMA GEMM, one wave = 16x16xK tile, no LDS.
__global__ __launch_bounds__(256) void hgemm16_kernel(
    const bh16* __restrict__ A, int lda, long aZ,
    const bh16* __restrict__ Bt, int ldb,
    const float* __restrict__ bias,
    const float* __restrict__ pre,
    float* __restrict__ Of, bh16* __restrict__ Ob, long oZ,
    int N, int K, int act,
    float* __restrict__ curf, bh16* __restrict__ curb,
    const float* __restrict__ scaleptr)
{
    const int z = blockIdx.z;
    A += (long)z * aZ;
    const int lane = threadIdx.x & 63, w = threadIdx.x >> 6;
    const int col0 = blockIdx.x * 64 + w * 16;
    const int ar = lane & 15;
    const int koff = (lane >> 4) * 8;
    const bh16* arow = A + (size_t)ar * lda + koff;
    const bh16* brow = Bt + (size_t)(col0 + ar) * ldb + koff;
    f32x4 acc = {0.f, 0.f, 0.f, 0.f};
    const int nkt = K >> 5;
    for (int kt0 = 0; kt0 < nkt; kt0 += 8) {
        bf16x8 av[8], bv[8];
        #pragma unroll
        for (int j = 0; j < 8; ++j) {
            av[j] = *(const bf16x8*)(arow + (size_t)(kt0 + j) * 32);
            bv[j] = *(const bf16x8*)(brow + (size_t)(kt0 + j) * 32);
        }
        #pragma unroll
        for (int j = 0; j < 8; ++j)
            acc = __builtin_amdgcn_mfma_f32_16x16x32_bf16(av[j], bv[j], acc, 0, 0, 0);
    }
    const int col = col0 + ar;
    float bs = bias ? bias[col] : 0.f;
    float sc = scaleptr ? *scaleptr : 0.f;
    #pragma unroll
    for (int r = 0; r < 4; ++r) {
        int row = (lane >> 4) * 4 + r;
        float v = acc[r] + bs;
        if (pre) v += pre[(size_t)row * N + col];
        if (act == ACT_SILU)      v = v / (1.f + expf(-v));
        else if (act == ACT_TANH) v = tanhf(v);
        if (curf) {
            size_t o = (size_t)row * 512 + col;
            float nc = curf[o] - v * sc;
            curf[o] = nc;
            curb[o] = __float2bfloat16(nc);
        } else {
            size_t o = (size_t)z * oZ + (size_t)row * N + col;
            if (Of) Of[o] = v;
            if (Ob) Ob[o] = __float2bfloat16(v);
        }
    }
}

// ---------------- head4 helpers ----------------
__device__ __forceinline__ void bload512(const bh16* Bt, int ldb, int col0, int lane, bf16x8 bv[16])
{
    const int ar = lane & 15;
    const int koff = (lane >> 4) * 8;
    const bh16* brow = Bt + (size_t)(col0 + ar) * ldb + koff;
    #pragma unroll
    for (int j = 0; j < 16; ++j)
        bv[j] = *(const bf16x8*)(brow + (size_t)j * 32);
}

// GEMV K=512: A from LDS (padded lda), B from persistent regs. Same accumulation
// order as hgemm16 (sequential j) -> bit-identical.
__device__ __forceinline__ f32x4 lmfma512(const unsigned short* A, int lda, int lane, const bf16x8 bv[16])
{
    const int ar = lane & 15;
    const int koff = (lane >> 4) * 8;
    const unsigned short* arow = A + (size_t)ar * lda + koff;
    f32x4 acc = {0.f, 0.f, 0.f, 0.f};
    #pragma unroll
    for (int j = 0; j < 16; ++j) {
        bf16x8 av = *(const bf16x8*)(arow + (size_t)j * 32);
        acc = __builtin_amdgcn_mfma_f32_16x16x32_bf16(av, bv[j], acc, 0, 0, 0);
    }
    return acc;
}

__device__ __forceinline__ f32x4 lslice(const unsigned short* A, int lda, const bh16* Bt, int ldb,
                                        int col0, int K, int lane)
{
    const int ar = lane & 15;
    const int koff = (lane >> 4) * 8;
    const unsigned short* arow = A + (size_t)ar * lda + koff;
    const bh16* brow = Bt + (size_t)(col0 + ar) * ldb + koff;
    f32x4 acc = {0.f, 0.f, 0.f, 0.f};
    const int nkt = K >> 5;
    for (int kt0 = 0; kt0 < nkt; kt0 += 8) {
        bf16x8 av[8], bv[8];
        #pragma unroll
        for (int j = 0; j < 8; ++j) {
            av[j] = *(const bf16x8*)(arow + (size_t)(kt0 + j) * 32);
            bv[j] = *(const bf16x8*)(brow + (size_t)(kt0 + j) * 32);
        }
        #pragma unroll
        for (int j = 0; j < 8; ++j)
            acc = __builtin_amdgcn_mfma_f32_16x16x32_bf16(av[j], bv[j], acc, 0, 0, 0);
    }
    return acc;
}

__device__ __forceinline__ void st_store(unsigned* st, int row, int colr, int lane, float v)
{
    float other = __shfl_xor(v, 1);
    if (!(lane & 1)) {
        unsigned lo = (unsigned)__bfloat16_as_ushort(__float2bfloat16(v));
        unsigned hi = (unsigned)__bfloat16_as_ushort(__float2bfloat16(other));
        __hip_atomic_store(st + ((row * 512 + colr) >> 1), lo | (hi << 16),
                           __ATOMIC_RELAXED, __HIP_MEMORY_SCOPE_AGENT);
    }
}

__device__ __forceinline__ void st_stage(unsigned short* ALds, const unsigned* st, int tid)
{
    const unsigned long long* st64 = (const unsigned long long*)st;
    for (int e = tid; e < 2048; e += 256) {
        unsigned long long uv = __hip_atomic_load(st64 + e, __ATOMIC_RELAXED, __HIP_MEMORY_SCOPE_AGENT);
        int row = e >> 7, cp = (e & 127) << 2;
        *(unsigned long long*)(ALds + row * 520 + cp) = uv;
    }
    __syncthreads();
}

__device__ __forceinline__ void gridbar(int* ctr, int* bar)
{
    __syncthreads();
    if (threadIdx.x == 0) {
        *bar += 8;
        __hip_atomic_fetch_add(ctr, 1, __ATOMIC_RELAXED, __HIP_MEMORY_SCOPE_AGENT);
        while (__hip_atomic_load(ctr, __ATOMIC_RELAXED, __HIP_MEMORY_SCOPE_AGENT) < *bar)
            __builtin_amdgcn_s_sleep(1);
    }
    __syncthreads();
}

// =====================================================================================
// Persistent head v4: dn1/dn2/dn3 weight slices resident in VGPRs across the whole
// diffusion loop (192 VGPRs); no in-loop weight traffic. 8 blocks, occupancy moot
// -> __launch_bounds__(256, 1) lifts the register cap.
__global__ __launch_bounds__(256, 1) void head4_kernel(
    const float* __restrict__ h,
    const bh16* __restrict__ mm1T, const float* __restrict__ mm1b,
    const bh16* __restrict__ mm2T, const float* __restrict__ mm2b,
    const bh16* __restrict__ dn1T,
    const bh16* __restrict__ dn2T, const float* __restrict__ dn2b,
    const bh16* __restrict__ dn3T, const float* __restrict__ dn3b,
    const bh16* __restrict__ outT, const float* __restrict__ outb,
    const float* __restrict__ pre1, const float* __restrict__ nsched,
    unsigned* __restrict__ stTM, unsigned* __restrict__ stCur,
    unsigned* __restrict__ stD1, unsigned* __restrict__ stD2,
    float* __restrict__ out, int* __restrict__ ctr)
{
    __shared__ __align__(16) unsigned short catL[16 * 1032];
    __shared__ __align__(16) unsigned short ALds[16 * 520];
    const int bx = blockIdx.x;
    const int tid = threadIdx.x;
    const int lane = tid & 63, w = tid >> 6;
    int bar = 0;
    const int col0 = bx * 64 + w * 16;
    const int colr = col0 + (lane & 15);
    const int row0 = (lane >> 4) * 4;
    bf16x8 bvA[16], bvB[16], bvC[16];

    // build cat (16 x 1024) in LDS
    for (int e = tid; e < 16 * 1024; e += 256) {
        int k = e & 1023, b = e >> 10;
        float v = (k < 512) ? h[((size_t)b * TT + 255) * DD + k]
                            : h[((size_t)b * TT + 254) * DD + (k - 512)];
        catL[b * 1032 + k] = __bfloat16_as_ushort(__float2bfloat16(v));
    }
    __syncthreads();

    // mm1: tm = tanh(cat @ mm1T + b) -> stTM
    {
        f32x4 acc = lslice(catL, 1032, mm1T, 1024, col0, 1024, lane);
        float bs = mm1b[colr];
        #pragma unroll
        for (int r = 0; r < 4; ++r)
            st_store(stTM, row0 + r, colr, lane, tanhf(acc[r] + bs));
    }
    bload512(mm2T, 512, col0, lane, bvA);    // mm2 weights (temp in bvA)
    gridbar(ctr, &bar);

    // mm2 + cur init
    float cur_reg[4];
    {
        st_stage(ALds, stTM, tid);
        f32x4 acc = lmfma512(ALds, 520, lane, bvA);
        float bs = mm2b[colr];
        #pragma unroll
        for (int r = 0; r < 4; ++r) {
            float cv = h[((size_t)(row0 + r) * TT + 255) * DD + colr] + acc[r] + bs;
            cur_reg[r] = cv;
            st_store(stCur, row0 + r, colr, lane, cv);
        }
    }
    // load ALL chain weights once; drain overlaps this barrier
    bload512(dn1T, 1024, col0, lane, bvA);
    bload512(dn2T, 512, col0, lane, bvB);
    bload512(dn3T, 512, col0, lane, bvC);
    gridbar(ctr, &bar);

    // diffusion chain: zero weight traffic inside
    for (int t = 0; t < SS; ++t) {
        float sc = nsched[t];
        {
            st_stage(ALds, stCur, tid);
            f32x4 acc = lmfma512(ALds, 520, lane, bvA);
            #pragma unroll
            for (int r = 0; r < 4; ++r) {
                float v = acc[r] + pre1[(size_t)t * 8192 + (row0 + r) * 512 + colr];
                v = v / (1.f + expf(-v));
                st_store(stD1, row0 + r, colr, lane, v);
            }
        }
        gridbar(ctr, &bar);
        {
            st_stage(ALds, stD1, tid);
            f32x4 acc = lmfma512(ALds, 520, lane, bvB);
            float bs = dn2b[colr];
            #pragma unroll
            for (int r = 0; r < 4; ++r) {
                float v = acc[r] + bs;
                v = v / (1.f + expf(-v));
                st_store(stD2, row0 + r, colr, lane, v);
            }
        }
        gridbar(ctr, &bar);
        {
            st_stage(ALds, stD2, tid);
            f32x4 acc = lmfma512(ALds, 520, lane, bvC);
            float bs = dn3b[colr];
            #pragma unroll
            for (int r = 0; r < 4; ++r) {
                float nc = cur_reg[r] - (acc[r] + bs) * sc;
                cur_reg[r] = nc;
                st_store(stCur, row0 + r, colr, lane, nc);
            }
        }
        if (t == SS - 1 && bx < 6)
            bload512(outT, 512, col0, lane, bvA);   // bvA (dn1) dead after last dn1 phase
        gridbar(ctr, &bar);
    }

    // out projection (N=384): blocks 0..5 store
    {
        st_stage(ALds, stCur, tid);
        if (bx < 6) {
            f32x4 acc = lmfma512(ALds, 520, lane, bvA);
            float bs = outb[colr];
            #pragma unroll
            for (int r = 0; r < 4; ++r)
                out[(size_t)(row0 + r) * 384 + colr] = acc[r] + bs;
        }
    }
}

// ---------------- wavelet: in-kernel filter softmax + dec (LDS tile) + interp ----------------
__global__ __launch_bounds__(256) void wave4_kernel(const bh16* __restrict__ hb,
                                                    const float* __restrict__ wav0,
                                                    const float* __restrict__ wav1,
                                                    const float* __restrict__ wav2,
                                                    const float* __restrict__ wav3,
                                                    int l,
                                                    bh16* __restrict__ comb)
{
    __shared__ float dtile[66 * 64];
    __shared__ float ftile[32 * 64];
    const int dblk = blockIdx.x;
    const int iy = blockIdx.y;
    const int b = blockIdx.z;
    const int i = iy >> 1, thalf = iy & 1;
    const int Karr[4] = {4, 8, 16, 32};
    const int K = Karr[i], sv = 2 << i, Ti = 128 >> i;
    const int tid = threadIdx.x;
    const int dbase = dblk * 64;
    if (tid < 64) {
        const float* wsrc = (i == 0) ? wav0 : (i == 1) ? wav1 : (i == 2) ? wav2 : wav3;
        const float* row = wsrc + ((size_t)l * DD + dbase + tid) * K;
        float mx = -1e30f;
        for (int k = 0; k < K; ++k) mx = fmaxf(mx, row[k]);
        float s = 0.f;
        for (int k = 0; k < K; ++k) { float e = expf(row[k] - mx); ftile[k*64 + tid] = e; s += e; }
        float inv = 1.f / s;
        for (int k = 0; k < K; ++k) ftile[k*64 + tid] *= inv;
    }
    const float invsv = 1.f / (float)sv;
    const int t0 = thalf * 128;
    float p0 = ((float)t0 + 0.5f) * invsv - 0.5f;
    p0 = fminf(fmaxf(p0, 0.f), (float)(Ti - 1));
    const int jbase = (int)p0;
    float p1 = ((float)(t0 + 127) + 0.5f) * invsv - 0.5f;
    p1 = fminf(fmaxf(p1, 0.f), (float)(Ti - 1));
    const int him = min((int)p1 + 1, Ti - 1);
    const int jcount = him - jbase + 1;     // <= 66
    __syncthreads();
    const bh16* hcol = hb + (size_t)b * (TT * DD) + dbase;
    for (int e = tid; e < jcount * 64; e += 256) {
        int jl = e >> 6, d0 = e & 63;
        int j = jbase + jl;
        int tb = j * sv - (K - 1);
        float acc = 0.f;
        #pragma unroll 4
        for (int k = 0; k < K; ++k) {
            int t = tb + k;
            if (t >= 0)
                acc += b2f(*(const unsigned short*)(hcol + (size_t)t * DD + d0)) * ftile[k * 64 + d0];
        }
        dtile[jl * 64 + d0] = acc;
    }
    __syncthreads();
    for (int e = tid; e < 128 * 64; e += 256) {
        int tl = e >> 6, d0 = e & 63;
        int t = t0 + tl;
        float pos = ((float)t + 0.5f) * invsv - 0.5f;
        pos = fminf(fmaxf(pos, 0.f), (float)(Ti - 1));
        int lo = (int)pos;
        int hi = min(lo + 1, Ti - 1);
        float w = pos - (float)lo;
        float v = dtile[(lo - jbase) * 64 + d0] * (1.f - w) + dtile[(hi - jbase) * 64 + d0] * w;
        comb[((size_t)b * TT + t) * 2048 + i * 512 + dbase + d0] = __float2bfloat16(v);
    }
}

// ---------------- h = layernorm(s0+s1+s2+s3 + h)*g + b, dual fp32+bf16 out ----------------
__global__ __launch_bounds__(256) void add_ln_kernel(const float* __restrict__ s0, const float* __restrict__ s1,
                                                     const float* __restrict__ s2, const float* __restrict__ s3,
                                                     float* __restrict__ h, bh16* __restrict__ hb,
                                                     const float* __restrict__ g, const float* __restrict__ be)
{
    int lane = threadIdx.x & 63, wid = threadIdx.x >> 6;
    size_t row = (size_t)blockIdx.x * 4 + wid;
    const float* sr0 = s0 + row * DD;
    const float* sr1 = s1 + row * DD;
    const float* sr2 = s2 + row * DD;
    const float* sr3 = s3 + row * DD;
    float* hr = h + row * DD;
    bh16* hbr = hb + row * DD;
    float xv[8]; float sum = 0.f;
    #pragma unroll
    for (int u = 0; u < 8; ++u) {
        int c = lane + u * 64;
        xv[u] = sr0[c] + sr1[c] + sr2[c] + sr3[c] + hr[c];
        sum += xv[u];
    }
    #pragma unroll
    for (int off = 32; off; off >>= 1) sum += __shfl_xor(sum, off);
    float mu = sum * (1.f / 512.f);
    float sq = 0.f;
    #pragma unroll
    for (int u = 0; u < 8; ++u) { float d = xv[u] - mu; sq += d * d; }
    #pragma unroll
    for (int off = 32; off; off >>= 1) sq += __shfl_xor(sq, off);
    float rstd = 1.f / sqrtf(sq * (1.f / 512.f) + 1e-5f);
    #pragma unroll
    for (int u = 0; u < 8; ++u) {
        int c = lane + u * 64;
        float v = (xv[u] - mu) * rstd * g[c] + be[c];
        hr[c] = v;
        hbr[c] = __float2bfloat16(v);
    }
}

// ---------------- weight transpose-convert ----------------
__global__ __launch_bounds__(256) void wtrans_kernel(const float* __restrict__ W, bh16* __restrict__ Wt,
                                                     int K, int N, long lstride)
{
    int l = blockIdx.z;
    const float* Wl = W + (size_t)l * K * N;
    bh16* Wo = Wt + (size_t)l * lstride;
    __shared__ float tile[32][33];
    int n0 = blockIdx.x * 32, k0 = blockIdx.y * 32;
    int lx = threadIdx.x & 31, ly = threadIdx.x >> 5;
    #pragma unroll
    for (int j = 0; j < 4; ++j) {
        int kk = ly + j * 8;
        tile[kk][lx] = Wl[(size_t)(k0 + kk) * N + n0 + lx];
    }
    __syncthreads();
    #pragma unroll
    for (int j = 0; j < 4; ++j) {
        int nr = ly + j * 8;
        Wo[(size_t)(n0 + nr) * K + k0 + lx] = __float2bfloat16(tile[lx][nr]);
    }
}

// ---------------- fused qkv|te1 transpose: grid (50, 16, 6) ----------------
__global__ __launch_bounds__(256) void wtrans4_kernel(const float* __restrict__ gq, const float* __restrict__ gk,
                                                      const float* __restrict__ gv, const float* __restrict__ te1,
                                                      bh16* __restrict__ qkvT)
{
    int bxx = blockIdx.x, l = blockIdx.z;
    const float* W; long off; int N; int n0;
    if (bxx < 16)      { W = gq;  off = 0;      N = 512; n0 = bxx * 32; }
    else if (bxx < 32) { W = gk;  off = 262144; N = 512; n0 = (bxx - 16) * 32; }
    else if (bxx < 48) { W = gv;  off = 524288; N = 512; n0 = (bxx - 32) * 32; }
    else               { W = te1; off = 786432; N = 64;  n0 = (bxx - 48) * 32; }
    const float* Wl = W + (size_t)l * 512 * N;
    bh16* Wo = qkvT + (size_t)l * 819200 + off;
    __shared__ float tile[32][33];
    int k0 = blockIdx.y * 32;
    int lx = threadIdx.x & 31, ly = threadIdx.x >> 5;
    #pragma unroll
    for (int j = 0; j < 4; ++j) {
        int kk = ly + j * 8;
        tile[kk][lx] = Wl[(size_t)(k0 + kk) * N + n0 + lx];
    }
    __syncthreads();
    #pragma unroll
    for (int j = 0; j < 4; ++j) {
        int nr = ly + j * 8;
        Wo[(size_t)(n0 + nr) * 512 + k0 + lx] = __float2bfloat16(tile[lx][nr]);
    }
}

// ---------------- fused head weight transpose: 1984 blocks ----------------
__global__ __launch_bounds__(256) void wtransH_kernel(
    const float* __restrict__ mm1w, const float* __restrict__ mm2w,
    const float* __restrict__ dn1w, const float* __restrict__ dn2w,
    const float* __restrict__ dn3w, const float* __restrict__ outw,
    bh16* __restrict__ mm1T, bh16* __restrict__ mm2T, bh16* __restrict__ dn1T,
    bh16* __restrict__ dn2T, bh16* __restrict__ dn3T, bh16* __restrict__ outT)
{
    int bx = blockIdx.x;
    const float* W; bh16* Wo; int K, N, bloc;
    if (bx < 512)       { W = mm1w; Wo = mm1T; K = 1024; N = 512; bloc = bx; }
    else if (bx < 768)  { W = mm2w; Wo = mm2T; K = 512;  N = 512; bloc = bx - 512; }
    else if (bx < 1280) { W = dn1w; Wo = dn1T; K = 1024; N = 512; bloc = bx - 768; }
    else if (bx < 1536) { W = dn2w; Wo = dn2T; K = 512;  N = 512; bloc = bx - 1280; }
    else if (bx < 1792) { W = dn3w; Wo = dn3T; K = 512;  N = 512; bloc = bx - 1536; }
    else                { W = outw; Wo = outT; K = 512;  N = 384; bloc = bx - 1792; }
    int nblk = N / 32;
    int n0 = (bloc % nblk) * 32, k0 = (bloc / nblk) * 32;
    __shared__ float tile[32][33];
    int lx = threadIdx.x & 31, ly = threadIdx.x >> 5;
    #pragma unroll
    for (int j = 0; j < 4; ++j) {
        int kk = ly + j * 8;
        tile[kk][lx] = W[(size_t)(k0 + kk) * N + n0 + lx];
    }
    __syncthreads();
    #pragma unroll
    for (int j = 0; j < 4; ++j) {
        int nr = ly + j * 8;
        Wo[(size_t)(n0 + nr) * K + k0 + lx] = __float2bfloat16(tile[lx][nr]);
    }
}

// ---------------- cc_w [L][O][I][3] f32 -> ccT [L][O][tap*512+I] bf16 ----------------
__global__ __launch_bounds__(256) void ccconv_kernel(const float* __restrict__ ccw, bh16* __restrict__ ccT)
{
    size_t idx = (size_t)blockIdx.x * 256 + threadIdx.x;   // 6*512*1536
    int i = idx & 511; size_t rem = idx >> 9;
    int tap = (int)(rem % 3); rem /= 3;
    int o = (int)(rem & 511); int l = (int)(rem >> 9);
    ccT[idx] = __float2bfloat16(ccw[(((size_t)l*512 + o)*512 + i)*3 + tap]);
}

// ---------------- qkv|te1 bias concat [L][1600] + fused-epilogue bias sum [L][512] ----------------
__global__ __launch_bounds__(256) void qkvbias_kernel(const float* __restrict__ qb_, const float* __restrict__ kb_,
                                                      const float* __restrict__ vb_, const float* __restrict__ t1b_,
                                                      float* __restrict__ ob,
                                                      const float* __restrict__ gob, const float* __restrict__ wrb,
                                                      const float* __restrict__ tdb, const float* __restrict__ ccb,
                                                      float* __restrict__ bsum)
{
    int idx = blockIdx.x * 256 + threadIdx.x;
    if (idx < 6 * 1600) {
        int l = idx / 1600, n = idx % 1600;
        float v = (n < 512) ? qb_[l*512 + n]
                : (n < 1024) ? kb_[l*512 + n - 512]
                : (n < 1536) ? vb_[l*512 + n - 1024]
                : t1b_[l*64 + n - 1536];
        ob[idx] = v;
    }
    if (idx < 6 * 512) {
        bsum[idx] = gob[idx] + wrb[idx] + tdb[idx] + ccb[idx];
    }
}

// ---------------- x f32 -> bf16 ----------------
__global__ __launch_bounds__(256) void convx_kernel(const float* __restrict__ x, bh16* __restrict__ xb)
{
    size_t idx = (size_t)blockIdx.x * 256 + threadIdx.x;
    xb[idx] = __float2bfloat16(x[idx]);
}

// ---------------- E matrix: row (t,b) = [sched[t]*noise[t,b,:] | temb[t]] ----------------
__global__ __launch_bounds__(256) void build_E_kernel(const float* __restrict__ noise, const float* __restrict__ sched,
                                                      bh16* __restrict__ E)
{
    int idx = blockIdx.x * 256 + threadIdx.x;   // 10*16*1024
    if (idx >= SS * BB * 1024) return;
    int k = idx & 1023; int rem = idx >> 10; int b = rem & 15; int t = rem >> 4;
    float v;
    if (k < 512) {
        v = sched[t] * noise[((size_t)t * BB + b) * 512 + k];
    } else {
        int j = k - 512;
        const float kfac = -9.210340371976184f / 255.f;
        v = (j < 256) ? sinf((float)t * expf((float)j * kfac))
                      : cosf((float)t * expf((float)(j - 256) * kfac));
    }
    E[idx] = __float2bfloat16(v);
}

// ---------------- init: zero page, loss, grid-barrier counter ----------------
__global__ void init_kernel(bh16* zp, float* loss, int* ctr)
{
    int t = threadIdx.x;
    if (t < 64) zp[t] = __float2bfloat16(0.f);
    if (t == 64) *loss = 0.f;
    if (t == 65) *ctr = 0;
}

__global__ void fail_kernel(float* p) { p[0] = 1e30f; }

// =====================================================================================
extern "C" void kernel_launch(void* const* d_in, const int* in_sizes, int n_in,
                              void* d_out, int out_size, void* d_ws, size_t ws_size,
                              hipStream_t stream)
{
    const float* x      = (const float*)d_in[0];
    const float* in_w   = (const float*)d_in[1];
    const float* in_b   = (const float*)d_in[2];
    const float* gq_w   = (const float*)d_in[3];
    const float* gq_b   = (const float*)d_in[4];
    const float* gk_w   = (const float*)d_in[5];
    const float* gk_b   = (const float*)d_in[6];
    const float* gv_w   = (const float*)d_in[7];
    const float* gv_b   = (const float*)d_in[8];
    const float* go_w   = (const float*)d_in[9];
    const float* go_b   = (const float*)d_in[10];
    const float* curv   = (const float*)d_in[11];
    const float* wav0   = (const float*)d_in[12];
    const float* wav1   = (const float*)d_in[13];
    const float* wav2   = (const float*)d_in[14];
    const float* wav3   = (const float*)d_in[15];
    const float* wrec_w = (const float*)d_in[16];
    const float* wrec_b = (const float*)d_in[17];
    const float* te1_w  = (const float*)d_in[18];
    const float* te1_b  = (const float*)d_in[19];
    const float* te2_w  = (const float*)d_in[20];
    const float* te2_b  = (const float*)d_in[21];
    const float* td1_w  = (const float*)d_in[22];
    const float* td1_b  = (const float*)d_in[23];
    const float* td2_w  = (const float*)d_in[24];
    const float* td2_b  = (const float*)d_in[25];
    const float* bd_w   = (const float*)d_in[26];
    const float* bd_b   = (const float*)d_in[27];
    const float* cc_w   = (const float*)d_in[28];
    const float* cc_b   = (const float*)d_in[29];
    const float* ln_g   = (const float*)d_in[30];
    const float* ln_b   = (const float*)d_in[31];
    const float* mm1_w  = (const float*)d_in[32];
    const float* mm1_b  = (const float*)d_in[33];
    const float* mm2_w  = (const float*)d_in[34];
    const float* mm2_b  = (const float*)d_in[35];
    const float* dn1_w  = (const float*)d_in[36];
    const float* dn1_b  = (const float*)d_in[37];
    const float* dn2_w  = (const float*)d_in[38];
    const float* dn2_b  = (const float*)d_in[39];
    const float* dn3_w  = (const float*)d_in[40];
    const float* dn3_b  = (const float*)d_in[41];
    const float* out_w  = (const float*)d_in[42];
    const float* out_b  = (const float*)d_in[43];
    const float* nsched = (const float*)d_in[44];
    const float* noise  = (const float*)d_in[45];
    float* out = (float*)d_out;
    float* ws  = (float*)d_ws;

    // ---- fp32 workspace layout (float offsets) ----
    const size_t o_h   = 0;          // 2097152
    const size_t o_dec = 2097152;    // 2097152 (s2 partial; pre1 for head)
    const size_t o_s   = 4194304;    // 2097152
    const size_t o_at  = 6619136;    // 8388608: comb (bf16, first half) + s3/s4 partials
    const size_t o_qkb = 15054848;   // 9600
    const size_t o_bs  = 15064448;   // 3072
    const size_t o_ctr = 15067520;   // 1 (int)
    const size_t FP32_TOTAL = 15095808;
    // ---- bf16 region (element offsets from bp) ----
    const size_t b_xb   = 0;          // 1572864
    const size_t b_hb   = 1572864;    // 2097152
    const size_t b_qkv  = 3670016;    // 6553600: packed qkv|t1 [4096][1600]
    const size_t b_pb   = 12320768;   // 8388608 (head scratch region)
    const size_t b_gmb  = 20709376;   // 2097152
    const size_t b_tdb  = 22806528;   // 2097152
    const size_t b_zp   = 25165824;   // 512
    const size_t b_inwT = 25166336;   // 196608
    const size_t b_qkvT = 25362944;   // 4915200
    const size_t b_goT  = 30278144;   // 1572864
    const size_t b_wrT  = 31851008;   // 6291456
    const size_t b_td1T = 38142464;   // 196608
    const size_t b_td2T = 38339072;   // 1572864
    const size_t b_te2T = 39911936;   // 24576
    const size_t b_ccT  = 39936512;   // 4718592
    const size_t BF16_TOTAL = 44655104;
    const size_t TOTAL_BYTES = FP32_TOTAL * 4 + BF16_TOTAL * 2;
    if (ws_size < TOTAL_BYTES) { fail_kernel<<<1, 1, 0, stream>>>(out); return; }

    float* h_   = ws + o_h;
    float* s2_  = ws + o_dec;
    float* s_   = ws + o_s;
    float* at_  = ws + o_at;
    float* s3_  = at_ + 4194304;
    float* s4_  = at_ + 6291456;
    float* qkvbias = ws + o_qkb;
    float* bsum = ws + o_bs;
    int*   ctr  = (int*)(ws + o_ctr);
    bh16* bp   = (bh16*)(ws + FP32_TOTAL);
    bh16* xb   = bp + b_xb;
    bh16* hb   = bp + b_hb;
    bh16* qkvb = bp + b_qkv;
    bh16* pb   = bp + b_pb;
    bh16* gmb  = bp + b_gmb;
    bh16* tdb  = bp + b_tdb;
    bh16* zp   = bp + b_zp;
    bh16* inwT = bp + b_inwT;
    bh16* qkvT = bp + b_qkvT;
    bh16* goT  = bp + b_goT;
    bh16* wrT  = bp + b_wrT;
    bh16* td1T = bp + b_td1T;
    bh16* td2T = bp + b_td2T;
    bh16* te2T = bp + b_te2T;
    bh16* ccT  = bp + b_ccT;
    bh16* combb = (bh16*)at_;

    // head bf16 scratch: aliased into pb region (dead during layers)
    bh16* dn1T  = pb;             // 524288
    bh16* dn2T  = pb + 524288;    // 262144
    bh16* dn3T  = pb + 786432;    // 262144
    bh16* mm1T  = pb + 1048576;   // 524288
    bh16* mm2T  = pb + 1572864;   // 262144
    bh16* outT  = pb + 1835008;   // 196608
    bh16* E16   = pb + 2031616;   // 163840
    float* pre1 = s2_;            // 81920 f32, aliases s2 after layers
    // head state (u32-packed bf16, agent-scope atomics): in s4_ area
    unsigned* stTM  = (unsigned*)s4_;          // 4096 u32 each
    unsigned* stCur = stTM + 4096;
    unsigned* stD1  = stTM + 8192;
    unsigned* stD2  = stTM + 12288;

    auto mgp = [&](const bh16* A, int lda, const bh16* Bt, int ldb,
                   const float* bias, float* Cf, bh16* Cb, int ldc,
                   int M, int N, int K, int shift, int accum, int act) {
        dim3 g((N + 63) / 64, M / 128, 1);
        mgemm_kernel<<<g, 256, 0, stream>>>(A, lda, Bt, ldb, bias, Cf, Cb, ldc, N, K,
                                            shift, accum, act, zp);
    };

    // ---- setup ----
    init_kernel<<<1, 128, 0, stream>>>(zp, out + BB * DIN, ctr);
    convx_kernel<<<BT * DIN / 256, 256, 0, stream>>>(x, xb);
    wtrans_kernel<<<dim3(DD/32, DIN/32, 1), 256, 0, stream>>>(in_w, inwT, DIN, DD, (long)DIN*DD);
    wtrans4_kernel<<<dim3(50, 16, 6), 256, 0, stream>>>(gq_w, gk_w, gv_w, te1_w, qkvT);
    qkvbias_kernel<<<38, 256, 0, stream>>>(gq_b, gk_b, gv_b, te1_b, qkvbias,
                                           go_b, wrec_b, td2_b, cc_b, bsum);
    wtrans_kernel<<<dim3(16, 16, 6), 256, 0, stream>>>(go_w, goT, DD, DD, (long)DD*DD);
    wtrans_kernel<<<dim3(16, 64, 6), 256, 0, stream>>>(wrec_w, wrT, 2048, DD, 2048L*DD);
    wtrans_kernel<<<dim3(16, 2, 6), 256, 0, stream>>>(td1_w, td1T, PP, DD, (long)PP*DD);
    wtrans_kernel<<<dim3(16, 16, 6), 256, 0, stream>>>(td2_w, td2T, DD, DD, (long)DD*DD);
    wtrans_kernel<<<dim3(2, 2, 6), 256, 0, stream>>>(te2_w, te2T, PP, PP, (long)PP*PP);
    ccconv_kernel<<<18432, 256, 0, stream>>>(cc_w, ccT);

    // h = x @ in_w + in_b  (fp32 + bf16)
    mgp(xb, DIN, inwT, DIN, in_b, h_, hb, DD, BT, DD, DIN, 0, 0, ACT_NONE);

    for (int l = 0; l < LL; ++l) {
        mgp(hb, DD, qkvT + (size_t)l*819200, DD, qkvbias + (size_t)l*1600,
            nullptr, qkvb, 1600, BT, 1600, DD, 0, 0, ACT_RELU_TAIL);
        fattn_kernel<<<dim3(4, 128), 256, 0, stream>>>(qkvb, curv + (size_t)l*HH, gmb);
        wave4_kernel<<<dim3(8, 8, 16), 256, 0, stream>>>(hb, wav0, wav1, wav2, wav3, l, combb);
        topo_kernel<<<dim3(8, 32), 256, 0, stream>>>(
            qkvb + 1536, te2T + (size_t)l*4096, te2_b + (size_t)l*PP,
            td1T + (size_t)l*32768, td1_b + (size_t)l*DD,
            bd_w + (size_t)l*PP*2, bd_b + (size_t)l*2, out + BB*DIN, tdb);
        fgemm_kernel<<<dim3(8, 32, 4), 256, 0, stream>>>(
            gmb, combb, tdb, hb,
            goT + (size_t)l*262144, wrT + (size_t)l*1048576,
            td2T + (size_t)l*262144, ccT + (size_t)l*786432,
            bsum + (size_t)l*512, s_, s2_, s3_, s4_, 1 << l, zp);
        add_ln_kernel<<<BT/4, 256, 0, stream>>>(s_, s2_, s3_, s4_, h_, hb, ln_g, ln_b);
    }

    // ---- head ----
    wtransH_kernel<<<1984, 256, 0, stream>>>(mm1_w, mm2_w, dn1_w, dn2_w, dn3_w, out_w,
                                             mm1T, mm2T, dn1T, dn2T, dn3T, outT);
    build_E_kernel<<<640, 256, 0, stream>>>(noise, nsched, E16);
    hgemm16_kernel<<<dim3(8, 1, SS), 256, 0, stream>>>(
        E16, 1024, 16*1024, dn1T, 1024, dn1_b, nullptr, pre1, nullptr, 8192,
        512, 1024, ACT_NONE, nullptr, nullptr, nullptr);
    head4_kernel<<<8, 256, 0, stream>>>(
        h_, mm1T, mm1_b, mm2T, mm2_b, dn1T, dn2T, dn2_b, dn3T, dn3_b,
        outT, out_b, pre1, nsched, stTM, stCur, stD1, stD2, out, ctr);
}